// Round 10
// baseline (2367.568 us; speedup 1.0000x reference)
//
#include <hip/hip_runtime.h>
#include <hip/hip_bf16.h>

#define DEV static __device__ __forceinline__

using short8 = __attribute__((ext_vector_type(8))) short;
using f32x4 = __attribute__((ext_vector_type(4))) float;

DEV short f2bf(float f) {
  union { float f; unsigned u; } x; x.f = f;
  unsigned r = x.u + 0x7fffu + ((x.u >> 16) & 1u);
  return (short)(r >> 16);
}

DEV float bf2f(short s) {
  union { unsigned u; float f; } x; x.u = ((unsigned)(unsigned short)s) << 16;
  return x.f;
}

DEV void gload16(const void* g, void* lds) {
  __builtin_amdgcn_global_load_lds(
      (const __attribute__((address_space(1))) void*)g,
      (__attribute__((address_space(3))) void*)lds, 16, 0, 0);
}

// Abramowitz-Stegun 7.1.26 erf, |err| <= 1.5e-7
DEV float erf_fast(float x) {
  float ax = fabsf(x);
  float t = __fdividef(1.f, 1.f + 0.3275911f * ax);
  float y = t * (0.254829592f + t * (-0.284496736f +
            t * (1.421413741f + t * (-1.453152027f + t * 1.061405429f))));
  float r = 1.f - y * __expf(-ax * ax);
  return copysignf(r, x);
}

// ---------------- weight transpose tile body: f32 [K][N] -> bf16 [N][K]
DEV void transpose_tile(const float* in, short* out, int K, int N, int tt, int nt,
                        int tid, short (*t)[72]) {
  const int n0 = (tt % nt) * 64, k0 = (tt / nt) * 64;
  #pragma unroll
  for (int p = 0; p < 4; ++p) {
    int r = p * 16 + (tid >> 4), c4 = tid & 15;
    float4 v = *reinterpret_cast<const float4*>(in + (size_t)(k0 + r) * N + n0 + c4 * 4);
    t[r][c4 * 4 + 0] = f2bf(v.x);
    t[r][c4 * 4 + 1] = f2bf(v.y);
    t[r][c4 * 4 + 2] = f2bf(v.z);
    t[r][c4 * 4 + 3] = f2bf(v.w);
  }
  __syncthreads();
  #pragma unroll
  for (int q = 0; q < 2; ++q) {
    int n = tid >> 2, kc = (tid & 3) + q * 4;
    short8 o;
    #pragma unroll
    for (int j = 0; j < 8; ++j) o[j] = t[kc * 8 + j][n];
    *reinterpret_cast<short8*>(out + (size_t)(n0 + n) * K + k0 + kc * 8) = o;
  }
}

// per-layer variant (fallback path)
__global__ __launch_bounds__(256) void transpose_all_k(
    const float* __restrict__ Wqkv, const float* __restrict__ Wo,
    const float* __restrict__ W1, const float* __restrict__ W2,
    short* __restrict__ wqkvT, short* __restrict__ woT,
    short* __restrict__ w1T, short* __restrict__ w2T)
{
  __shared__ short t[64][72];
  const int b = blockIdx.x, tid = threadIdx.x;
  const float* in; short* out; int K, N, tt, nt;
  if (b < 432)       { in = Wqkv; out = wqkvT; K = 768;  N = 2304; tt = b;        nt = 36; }
  else if (b < 576)  { in = Wo;   out = woT;   K = 768;  N = 768;  tt = b - 432;  nt = 12; }
  else if (b < 1152) { in = W1;   out = w1T;   K = 768;  N = 3072; tt = b - 576;  nt = 48; }
  else               { in = W2;   out = w2T;   K = 3072; N = 768;  tt = b - 1152; nt = 12; }
  transpose_tile(in, out, K, N, tt, nt, tid, t);
}

// all-12-layers variant (blockIdx.z = layer)
__global__ __launch_bounds__(256) void transpose12_k(
    const float* __restrict__ Wqkv, const float* __restrict__ Wo,
    const float* __restrict__ W1, const float* __restrict__ W2,
    short* __restrict__ wqkvT, short* __restrict__ woT,
    short* __restrict__ w1T, short* __restrict__ w2T)
{
  __shared__ short t[64][72];
  const int b = blockIdx.x, l = blockIdx.z, tid = threadIdx.x;
  const float* in; short* out; int K, N, tt, nt;
  if (b < 432)       { in = Wqkv + (size_t)l * 768 * 2304; out = wqkvT + (size_t)l * 2304 * 768; K = 768;  N = 2304; tt = b;        nt = 36; }
  else if (b < 576)  { in = Wo   + (size_t)l * 768 * 768;  out = woT   + (size_t)l * 768 * 768;  K = 768;  N = 768;  tt = b - 432;  nt = 12; }
  else if (b < 1152) { in = W1   + (size_t)l * 768 * 3072; out = w1T   + (size_t)l * 3072 * 768; K = 768;  N = 3072; tt = b - 576;  nt = 48; }
  else               { in = W2   + (size_t)l * 3072 * 768; out = w2T   + (size_t)l * 768 * 3072; K = 3072; N = 768;  tt = b - 1152; nt = 12; }
  transpose_tile(in, out, K, N, tt, nt, tid, t);
}

// ---------------- GEMM (proven round-8 structure, BK=64 as 2x32 subtiles):
// C = A[M,K](bf16) @ Bt[N,K]^T + bias. EPI 0: bias->bf16; 1: bias+gelu->bf16
template <int BM, int EPI>
__global__ __launch_bounds__(256) void gemm_bt(
    const short* __restrict__ A, const short* __restrict__ Bt,
    const float* __restrict__ bias, const float* __restrict__ resid,
    void* __restrict__ Cout, int M, int Nn, int K)
{
  constexpr int AW = BM / 64;
  constexpr int MI = BM / 32;
  __shared__ short As[2 * BM * 32];
  __shared__ short Bs[2 * 128 * 32];
  const int tid = threadIdx.x, lane = tid & 63, w = tid >> 6;
  const int wr = w >> 1, wc = w & 1;
  const int l15 = lane & 15, l4 = lane >> 4;
  const int m0 = blockIdx.y * BM, n0 = blockIdx.x * 128;
  const int crow = lane >> 2, ccol = (lane & 3) * 8;

  f32x4 acc[MI][4] = {};

  for (int k0 = 0; k0 < K; k0 += 64) {
    #pragma unroll
    for (int ks = 0; ks < 2; ++ks) {
      #pragma unroll
      for (int s = 0; s < AW; ++s) {
        int c = w * AW + s;
        gload16(A + (size_t)(m0 + c * 16 + crow) * K + k0 + ks * 32 + ccol,
                &As[ks * BM * 32 + c * 512]);
      }
      #pragma unroll
      for (int s = 0; s < 2; ++s) {
        int c = w * 2 + s;
        gload16(Bt + (size_t)(n0 + c * 16 + crow) * K + k0 + ks * 32 + ccol,
                &Bs[ks * 128 * 32 + c * 512]);
      }
    }
    __syncthreads();

    #pragma unroll
    for (int ks = 0; ks < 2; ++ks) {
      short8 af[MI], bfr[4];
      #pragma unroll
      for (int i = 0; i < MI; ++i)
        af[i] = *reinterpret_cast<const short8*>(
            &As[ks * BM * 32 + (wr * (BM / 2) + i * 16 + l15) * 32 + l4 * 8]);
      #pragma unroll
      for (int j = 0; j < 4; ++j)
        bfr[j] = *reinterpret_cast<const short8*>(
            &Bs[ks * 128 * 32 + (wc * 64 + j * 16 + l15) * 32 + l4 * 8]);
      #pragma unroll
      for (int i = 0; i < MI; ++i)
        #pragma unroll
        for (int j = 0; j < 4; ++j)
          acc[i][j] = __builtin_amdgcn_mfma_f32_16x16x32_bf16(af[i], bfr[j], acc[i][j], 0, 0, 0);
    }
    __syncthreads();
  }

  #pragma unroll
  for (int i = 0; i < MI; ++i) {
    #pragma unroll
    for (int j = 0; j < 4; ++j) {
      #pragma unroll
      for (int r = 0; r < 4; ++r) {
        int row = m0 + wr * (BM / 2) + i * 16 + l4 * 4 + r;
        int col = n0 + wc * 64 + j * 16 + l15;
        float v = acc[i][j][r] + bias[col];
        if constexpr (EPI == 1) v = 0.5f * v * (1.0f + erf_fast(v * 0.70710678118654752f));
        ((short*)Cout)[(size_t)row * Nn + col] = f2bf(v);
      }
    }
  }
}

// ---------------- split-K GEMM (BK=64, 4-way): bf16 partials, z in {0..3}
__global__ __launch_bounds__(256) void gemm_sk(
    const short* __restrict__ A, const short* __restrict__ Bt,
    short* __restrict__ p0, short* __restrict__ p1,
    short* __restrict__ p2, short* __restrict__ p3,
    int M, int Nn, int Kstride, int Klen)
{
  __shared__ short As[2 * 128 * 32];
  __shared__ short Bs[2 * 128 * 32];
  const int tid = threadIdx.x, lane = tid & 63, w = tid >> 6;
  const int wr = w >> 1, wc = w & 1;
  const int l15 = lane & 15, l4 = lane >> 4;
  const int m0 = blockIdx.y * 128, n0 = blockIdx.x * 128;
  const int koff = blockIdx.z * Klen;
  const int crow = lane >> 2, ccol = (lane & 3) * 8;

  f32x4 acc[4][4] = {};

  for (int k0 = 0; k0 < Klen; k0 += 64) {
    #pragma unroll
    for (int ks = 0; ks < 2; ++ks) {
      #pragma unroll
      for (int s = 0; s < 2; ++s) {
        int c = w * 2 + s;
        gload16(A + (size_t)(m0 + c * 16 + crow) * Kstride + koff + k0 + ks * 32 + ccol,
                &As[ks * 4096 + c * 512]);
      }
      #pragma unroll
      for (int s = 0; s < 2; ++s) {
        int c = w * 2 + s;
        gload16(Bt + (size_t)(n0 + c * 16 + crow) * Kstride + koff + k0 + ks * 32 + ccol,
                &Bs[ks * 4096 + c * 512]);
      }
    }
    __syncthreads();

    #pragma unroll
    for (int ks = 0; ks < 2; ++ks) {
      short8 af[4], bfr[4];
      #pragma unroll
      for (int i = 0; i < 4; ++i)
        af[i] = *reinterpret_cast<const short8*>(
            &As[ks * 4096 + (wr * 64 + i * 16 + l15) * 32 + l4 * 8]);
      #pragma unroll
      for (int j = 0; j < 4; ++j)
        bfr[j] = *reinterpret_cast<const short8*>(
            &Bs[ks * 4096 + (wc * 64 + j * 16 + l15) * 32 + l4 * 8]);
      #pragma unroll
      for (int i = 0; i < 4; ++i)
        #pragma unroll
        for (int j = 0; j < 4; ++j)
          acc[i][j] = __builtin_amdgcn_mfma_f32_16x16x32_bf16(af[i], bfr[j], acc[i][j], 0, 0, 0);
    }
    __syncthreads();
  }

  short* P = (blockIdx.z == 0) ? p0 : (blockIdx.z == 1) ? p1 : (blockIdx.z == 2) ? p2 : p3;
  #pragma unroll
  for (int i = 0; i < 4; ++i)
    #pragma unroll
    for (int j = 0; j < 4; ++j)
      #pragma unroll
      for (int r = 0; r < 4; ++r) {
        int row = m0 + wr * 64 + i * 16 + l4 * 4 + r;
        int col = n0 + wc * 64 + j * 16 + l15;
        P[(size_t)row * Nn + col] = f2bf(acc[i][j][r]);
      }
}

// ---------------- Flash attention, KVBLK=128: qkv[4096][2304] bf16 -> out bf16
// LDS 52.7KB -> 3 blocks/CU == grid density (768 blocks / 256 CU), so no occupancy loss.
__global__ __launch_bounds__(256) void attn_k(
    const short* __restrict__ qkv, const int* __restrict__ amask,
    short* __restrict__ out)
{
  __shared__ short Kl[128][72];     // K tile [ktok][dh]
  __shared__ short Vt[64][132];     // V^T tile [dh][ktok]
  __shared__ short Pl[4][16][136];  // per-wave P [q][ktok]
  const int b = blockIdx.z, h = blockIdx.y, qt = blockIdx.x;
  const int tid = threadIdx.x, lane = tid & 63, w = tid >> 6;
  const int l15 = lane & 15, l4 = lane >> 4;
  const int tok0 = b * 512;
  const int q0 = qt * 64 + w * 16;

  short8 qf[2];
  #pragma unroll
  for (int kk = 0; kk < 2; ++kk)
    qf[kk] = *reinterpret_cast<const short8*>(
        qkv + (size_t)(tok0 + q0 + l15) * 2304 + h * 64 + kk * 32 + l4 * 8);

  f32x4 oacc[4] = {};
  float mrow[4], lrow[4];
  #pragma unroll
  for (int r = 0; r < 4; ++r) { mrow[r] = -1e30f; lrow[r] = 0.f; }

  for (int kt0 = 0; kt0 < 512; kt0 += 128) {
    // stage K tile: 128 x 64
    #pragma unroll
    for (int i = 0; i < 4; ++i) {
      int c = tid + i * 256;
      int r = c >> 3, dc = c & 7;
      short8 v = *reinterpret_cast<const short8*>(
          qkv + (size_t)(tok0 + kt0 + r) * 2304 + 768 + h * 64 + dc * 8);
      *reinterpret_cast<short8*>(&Kl[r][dc * 8]) = v;
    }
    // stage V tile transposed: [dh][128]
    #pragma unroll
    for (int i = 0; i < 4; ++i) {
      int c = tid + i * 256;
      int r = c >> 3, dc = c & 7;
      short8 v = *reinterpret_cast<const short8*>(
          qkv + (size_t)(tok0 + kt0 + r) * 2304 + 1536 + h * 64 + dc * 8);
      #pragma unroll
      for (int j = 0; j < 8; ++j) Vt[dc * 8 + j][r] = v[j];
    }
    __syncthreads();

    // S = Q K^T : 8 tiles of 16 ktok
    f32x4 sacc[8] = {};
    #pragma unroll
    for (int t = 0; t < 8; ++t) {
      #pragma unroll
      for (int kk = 0; kk < 2; ++kk) {
        short8 kf = *reinterpret_cast<const short8*>(&Kl[t * 16 + l15][kk * 32 + l4 * 8]);
        sacc[t] = __builtin_amdgcn_mfma_f32_16x16x32_bf16(qf[kk], kf, sacc[t], 0, 0, 0);
      }
    }
    float p[8][4];
    #pragma unroll
    for (int t = 0; t < 8; ++t) {
      int ktok = kt0 + t * 16 + l15;
      float biasv = amask[b * 512 + ktok] ? 0.f : -1e9f;
      #pragma unroll
      for (int r = 0; r < 4; ++r) p[t][r] = sacc[t][r] * 0.125f + biasv;
    }
    // online softmax: one chain per 128 tokens (was per 64)
    #pragma unroll
    for (int r = 0; r < 4; ++r) {
      float mx = p[0][r];
      #pragma unroll
      for (int t = 1; t < 8; ++t) mx = fmaxf(mx, p[t][r]);
      #pragma unroll
      for (int s = 1; s <= 8; s <<= 1) mx = fmaxf(mx, __shfl_xor(mx, s, 64));
      float mnew = fmaxf(mrow[r], mx);
      float alpha = __expf(mrow[r] - mnew);
      mrow[r] = mnew;
      float sum = 0.f;
      #pragma unroll
      for (int t = 0; t < 8; ++t) { p[t][r] = __expf(p[t][r] - mnew); sum += p[t][r]; }
      #pragma unroll
      for (int s = 1; s <= 8; s <<= 1) sum += __shfl_xor(sum, s, 64);
      lrow[r] = lrow[r] * alpha + sum;
      #pragma unroll
      for (int t = 0; t < 4; ++t) oacc[t][r] *= alpha;
    }
    // P -> per-wave LDS (wave-private, no cross-wave barrier needed)
    #pragma unroll
    for (int t = 0; t < 8; ++t)
      #pragma unroll
      for (int r = 0; r < 4; ++r)
        Pl[w][l4 * 4 + r][t * 16 + l15] = f2bf(p[t][r]);
    // O += P V : 4 k-blocks of 32
    #pragma unroll
    for (int kk = 0; kk < 4; ++kk) {
      short8 pf = *reinterpret_cast<const short8*>(&Pl[w][l15][kk * 32 + l4 * 8]);
      #pragma unroll
      for (int t = 0; t < 4; ++t) {
        const unsigned* vp = reinterpret_cast<const unsigned*>(&Vt[t * 16 + l15][0]);
        union { short8 s; unsigned u[4]; } vu;
        #pragma unroll
        for (int w2 = 0; w2 < 4; ++w2) vu.u[w2] = vp[kk * 16 + l4 * 4 + w2];
        oacc[t] = __builtin_amdgcn_mfma_f32_16x16x32_bf16(pf, vu.s, oacc[t], 0, 0, 0);
      }
    }
    __syncthreads();
  }

  #pragma unroll
  for (int t = 0; t < 4; ++t)
    #pragma unroll
    for (int r = 0; r < 4; ++r) {
      int tok = tok0 + q0 + l4 * 4 + r;
      int dh = t * 16 + l15;
      out[(size_t)tok * 768 + h * 64 + dh] = f2bf(oacc[t][r] / lrow[r]);
    }
}

// ---------------- LN of (p0+p1+p2+p3 + bias + resid): bf16 partials -> f32 + bf16 out
__global__ __launch_bounds__(256) void ln2_k(
    const short* __restrict__ p0, const short* __restrict__ p1,
    const short* __restrict__ p2, const short* __restrict__ p3,
    const float* __restrict__ bias, const float* __restrict__ resid,
    const float* __restrict__ g, const float* __restrict__ be,
    float* __restrict__ xf, short* __restrict__ xb)
{
  const int t = blockIdx.x, tid = threadIdx.x;
  const size_t base = (size_t)t * 768;
  float v[3], s = 0.f, ss = 0.f;
  #pragma unroll
  for (int i = 0; i < 3; ++i) {
    int c = tid + i * 256;
    v[i] = (bf2f(p0[base + c]) + bf2f(p1[base + c]))
         + (bf2f(p2[base + c]) + bf2f(p3[base + c]))
         + bias[c] + resid[base + c];
    s += v[i]; ss += v[i] * v[i];
  }
  __shared__ float red[4][2];
  #pragma unroll
  for (int m = 1; m <= 32; m <<= 1) { s += __shfl_xor(s, m, 64); ss += __shfl_xor(ss, m, 64); }
  int w = tid >> 6;
  if ((tid & 63) == 0) { red[w][0] = s; red[w][1] = ss; }
  __syncthreads();
  s = red[0][0] + red[1][0] + red[2][0] + red[3][0];
  ss = red[0][1] + red[1][1] + red[2][1] + red[3][1];
  float mean = s * (1.f / 768.f);
  float var = ss * (1.f / 768.f) - mean * mean;
  float rs = rsqrtf(var + 1e-12f);
  #pragma unroll
  for (int i = 0; i < 3; ++i) {
    int c = tid + i * 256;
    float o = (v[i] - mean) * rs * g[c] + be[c];
    xf[base + c] = o;
    xb[base + c] = f2bf(o);
  }
}

// ---------------- embedding + LN
__global__ __launch_bounds__(256) void embed_ln_k(
    const int* __restrict__ ids, const float* __restrict__ tok_emb,
    const float* __restrict__ pos_emb, const float* __restrict__ g,
    const float* __restrict__ be, float* __restrict__ xf, short* __restrict__ xb)
{
  const int t = blockIdx.x, tid = threadIdx.x;
  const int id = ids[t], sp = t & 511;
  float v[3], s = 0.f, ss = 0.f;
  #pragma unroll
  for (int i = 0; i < 3; ++i) {
    int c = tid + i * 256;
    v[i] = tok_emb[(size_t)id * 768 + c] + pos_emb[(size_t)sp * 768 + c];
    s += v[i]; ss += v[i] * v[i];
  }
  __shared__ float red[4][2];
  #pragma unroll
  for (int m = 1; m <= 32; m <<= 1) { s += __shfl_xor(s, m, 64); ss += __shfl_xor(ss, m, 64); }
  int w = tid >> 6;
  if ((tid & 63) == 0) { red[w][0] = s; red[w][1] = ss; }
  __syncthreads();
  s = red[0][0] + red[1][0] + red[2][0] + red[3][0];
  ss = red[0][1] + red[1][1] + red[2][1] + red[3][1];
  float mean = s * (1.f / 768.f);
  float var = ss * (1.f / 768.f) - mean * mean;
  float rs = rsqrtf(var + 1e-12f);
  #pragma unroll
  for (int i = 0; i < 3; ++i) {
    int c = tid + i * 256;
    float o = (v[i] - mean) * rs * g[c] + be[c];
    xf[(size_t)t * 768 + c] = o;
    xb[(size_t)t * 768 + c] = f2bf(o);
  }
}

// ---------------- gather/scatter (parallel): cls + sentinel rows -> out[8][64][768]
__global__ __launch_bounds__(512) void gather_k(
    const int* __restrict__ ids, const float* __restrict__ x, float* __restrict__ out)
{
  const int doc = blockIdx.x, tid = threadIdx.x;
  const int lane = tid & 63, w = tid >> 6;
  __shared__ int src[64];
  __shared__ int wave_sent[8];
  __shared__ int cls_pos;
  if (tid < 64) src[tid] = -1;
  if (tid == 0) cls_pos = 0x7fffffff;
  __syncthreads();

  const int id = ids[doc * 512 + tid];
  const bool is_sent = (id == 103);
  const unsigned long long m = __ballot(is_sent);
  if (lane == 0) wave_sent[w] = __popcll(m);
  if (id == 102) atomicMin(&cls_pos, tid);
  __syncthreads();

  int total = 0, prefix = 0;
  #pragma unroll
  for (int i = 0; i < 8; ++i) {
    int c = wave_sent[i];
    if (i < w) prefix += c;
    total += c;
  }
  if (is_sent) {
    unsigned long long lt = lane ? (~0ULL >> (64 - lane)) : 0ULL;
    int d = 1 + prefix + __popcll(m & lt);
    if (d < total && d < 64) src[d] = tid;
  }
  if (tid == 0 && total > 0 && cls_pos != 0x7fffffff) src[0] = cls_pos;
  __syncthreads();

  for (int i = tid; i < 64 * 192; i += 512) {
    int row = i / 192, c4 = i - row * 192;
    int sp = src[row];
    float4 v = make_float4(0.f, 0.f, 0.f, 0.f);
    if (sp >= 0)
      v = reinterpret_cast<const float4*>(x + (size_t)(doc * 512 + sp) * 768)[c4];
    reinterpret_cast<float4*>(out + (size_t)doc * 64 * 768)[i] = v;
  }
}

extern "C" void kernel_launch(void* const* d_in, const int* in_sizes, int n_in,
                              void* d_out, int out_size, void* d_ws, size_t ws_size,
                              hipStream_t stream)
{
  const int* ids = (const int*)d_in[0];
  const int* am = (const int*)d_in[1];
  const float* tok_emb = (const float*)d_in[2];
  const float* pos_emb = (const float*)d_in[3];
  const float* eg = (const float*)d_in[4];
  const float* eb = (const float*)d_in[5];
  const float* Wqkv = (const float*)d_in[6];
  const float* bqkv = (const float*)d_in[7];
  const float* Wo = (const float*)d_in[8];
  const float* bo = (const float*)d_in[9];
  const float* g1 = (const float*)d_in[10];
  const float* b1n = (const float*)d_in[11];
  const float* W1 = (const float*)d_in[12];
  const float* b1f = (const float*)d_in[13];
  const float* W2 = (const float*)d_in[14];
  const float* b2f = (const float*)d_in[15];
  const float* g2 = (const float*)d_in[16];
  const float* b2n = (const float*)d_in[17];

  char* ws = (char*)d_ws;
  float* x_f   = (float*)(ws);                  // residual stream (f32)
  short* x_b   = (short*)(ws + 12582912);       // residual (bf16)
  float* x2_f  = (float*)(ws + 18874368);       // post-LN1 (f32)
  short* x2_b  = (short*)(ws + 31457280);       // post-LN1 (bf16)
  short* pp0   = (short*)(ws + 37748736);       // split-K partial 0
  short* pp1   = (short*)(ws + 37748736 + 6291456);
  short* qkv   = (short*)(ws + 50331648);       // QKV (bf16, 18.9MB)
  short* pp2   = (short*)(ws + 50331648);       // partial 2 (aliases dead qkv)
  short* pp3   = (short*)(ws + 50331648 + 6291456);
  short* attn  = (short*)(ws + 69206016);       // attn out
  short* hb    = (short*)(ws + 75497472);       // FFN1 out (25MB)
  const size_t WQ = 2304ull * 768, WO = 768ull * 768, W1S = 3072ull * 768, W2S = 768ull * 3072;
  const size_t NEED_ALL = 100663296ull + 12ull * (WQ + WO + W1S + W2S) * 2ull; // ~258 MB
  const bool big = ws_size >= NEED_ALL;

  short* wqkvT = (short*)(ws + 100663296);
  short* woT, *w1T, *w2T;
  if (big) {
    woT = wqkvT + 12 * WQ;
    w1T = woT + 12 * WO;
    w2T = w1T + 12 * W1S;
  } else {
    woT = (short*)(ws + 104202240);
    w1T = (short*)(ws + 105381888);
    w2T = (short*)(ws + 110100480);
  }

  embed_ln_k<<<4096, 256, 0, stream>>>(ids, tok_emb, pos_emb, eg, eb, x_f, x_b);

  if (big)
    transpose12_k<<<dim3(1728, 1, 12), 256, 0, stream>>>(
        Wqkv, Wo, W1, W2, wqkvT, woT, w1T, w2T);

  for (int l = 0; l < 12; ++l) {
    short *wq, *wo, *w1, *w2;
    if (big) {
      wq = wqkvT + l * WQ; wo = woT + l * WO; w1 = w1T + l * W1S; w2 = w2T + l * W2S;
    } else {
      transpose_all_k<<<1728, 256, 0, stream>>>(
          Wqkv + (size_t)l * 768 * 2304, Wo + (size_t)l * 768 * 768,
          W1 + (size_t)l * 768 * 3072, W2 + (size_t)l * 3072 * 768,
          wqkvT, woT, w1T, w2T);
      wq = wqkvT; wo = woT; w1 = w1T; w2 = w2T;
    }

    gemm_bt<128, 0><<<dim3(18, 32), 256, 0, stream>>>(
        x_b, wq, bqkv + (size_t)l * 2304, nullptr, qkv, 4096, 2304, 768);
    attn_k<<<dim3(8, 12, 8), 256, 0, stream>>>(qkv, am, attn);

    gemm_sk<<<dim3(6, 32, 4), 256, 0, stream>>>(
        attn, wo, pp0, pp1, pp2, pp3, 4096, 768, 768, 192);
    ln2_k<<<4096, 256, 0, stream>>>(
        pp0, pp1, pp2, pp3, bo + (size_t)l * 768, x_f,
        g1 + (size_t)l * 768, b1n + (size_t)l * 768, x2_f, x2_b);

    gemm_bt<128, 1><<<dim3(24, 32), 256, 0, stream>>>(
        x2_b, w1, b1f + (size_t)l * 3072, nullptr, hb, 4096, 3072, 768);

    gemm_sk<<<dim3(6, 32, 4), 256, 0, stream>>>(
        hb, w2, pp0, pp1, pp2, pp3, 4096, 768, 3072, 768);
    ln2_k<<<4096, 256, 0, stream>>>(
        pp0, pp1, pp2, pp3, b2f + (size_t)l * 768, x2_f,
        g2 + (size_t)l * 768, b2n + (size_t)l * 768, x_f, x_b);
  }

  gather_k<<<8, 512, 0, stream>>>(ids, x_f, (float*)d_out);
}

// Round 11
// 2345.627 us; speedup vs baseline: 1.0094x; 1.0094x over previous
//
#include <hip/hip_runtime.h>
#include <hip/hip_bf16.h>

#define DEV static __device__ __forceinline__

using short8 = __attribute__((ext_vector_type(8))) short;
using f32x4 = __attribute__((ext_vector_type(4))) float;

DEV short f2bf(float f) {
  union { float f; unsigned u; } x; x.f = f;
  unsigned r = x.u + 0x7fffu + ((x.u >> 16) & 1u);
  return (short)(r >> 16);
}

DEV float bf2f(short s) {
  union { unsigned u; float f; } x; x.u = ((unsigned)(unsigned short)s) << 16;
  return x.f;
}

DEV unsigned pack2bf(float a, float b) {
  return (unsigned)(unsigned short)f2bf(a) | ((unsigned)(unsigned short)f2bf(b) << 16);
}

DEV void gload16(const void* g, void* lds) {
  __builtin_amdgcn_global_load_lds(
      (const __attribute__((address_space(1))) void*)g,
      (__attribute__((address_space(3))) void*)lds, 16, 0, 0);
}

// Abramowitz-Stegun 7.1.26 erf, |err| <= 1.5e-7
DEV float erf_fast(float x) {
  float ax = fabsf(x);
  float t = __fdividef(1.f, 1.f + 0.3275911f * ax);
  float y = t * (0.254829592f + t * (-0.284496736f +
            t * (1.421413741f + t * (-1.453152027f + t * 1.061405429f))));
  float r = 1.f - y * __expf(-ax * ax);
  return copysignf(r, x);
}

// ---------------- weight transpose tile body: f32 [K][N] -> bf16 [N][K]
// stride 76 (was 72): read bank = (16(kc&1)+6j+n/2)%32 -> 4-way (was 8-way)
DEV void transpose_tile(const float* in, short* out, int K, int N, int tt, int nt,
                        int tid, short (*t)[76]) {
  const int n0 = (tt % nt) * 64, k0 = (tt / nt) * 64;
  #pragma unroll
  for (int p = 0; p < 4; ++p) {
    int r = p * 16 + (tid >> 4), c4 = tid & 15;
    float4 v = *reinterpret_cast<const float4*>(in + (size_t)(k0 + r) * N + n0 + c4 * 4);
    t[r][c4 * 4 + 0] = f2bf(v.x);
    t[r][c4 * 4 + 1] = f2bf(v.y);
    t[r][c4 * 4 + 2] = f2bf(v.z);
    t[r][c4 * 4 + 3] = f2bf(v.w);
  }
  __syncthreads();
  #pragma unroll
  for (int q = 0; q < 2; ++q) {
    int n = tid >> 2, kc = (tid & 3) + q * 4;
    short8 o;
    #pragma unroll
    for (int j = 0; j < 8; ++j) o[j] = t[kc * 8 + j][n];
    *reinterpret_cast<short8*>(out + (size_t)(n0 + n) * K + k0 + kc * 8) = o;
  }
}

// per-layer variant (fallback path)
__global__ __launch_bounds__(256) void transpose_all_k(
    const float* __restrict__ Wqkv, const float* __restrict__ Wo,
    const float* __restrict__ W1, const float* __restrict__ W2,
    short* __restrict__ wqkvT, short* __restrict__ woT,
    short* __restrict__ w1T, short* __restrict__ w2T)
{
  __shared__ short t[64][76];
  const int b = blockIdx.x, tid = threadIdx.x;
  const float* in; short* out; int K, N, tt, nt;
  if (b < 432)       { in = Wqkv; out = wqkvT; K = 768;  N = 2304; tt = b;        nt = 36; }
  else if (b < 576)  { in = Wo;   out = woT;   K = 768;  N = 768;  tt = b - 432;  nt = 12; }
  else if (b < 1152) { in = W1;   out = w1T;   K = 768;  N = 3072; tt = b - 576;  nt = 48; }
  else               { in = W2;   out = w2T;   K = 3072; N = 768;  tt = b - 1152; nt = 12; }
  transpose_tile(in, out, K, N, tt, nt, tid, t);
}

// all-12-layers variant (blockIdx.z = layer)
__global__ __launch_bounds__(256) void transpose12_k(
    const float* __restrict__ Wqkv, const float* __restrict__ Wo,
    const float* __restrict__ W1, const float* __restrict__ W2,
    short* __restrict__ wqkvT, short* __restrict__ woT,
    short* __restrict__ w1T, short* __restrict__ w2T)
{
  __shared__ short t[64][76];
  const int b = blockIdx.x, l = blockIdx.z, tid = threadIdx.x;
  const float* in; short* out; int K, N, tt, nt;
  if (b < 432)       { in = Wqkv + (size_t)l * 768 * 2304; out = wqkvT + (size_t)l * 2304 * 768; K = 768;  N = 2304; tt = b;        nt = 36; }
  else if (b < 576)  { in = Wo   + (size_t)l * 768 * 768;  out = woT   + (size_t)l * 768 * 768;  K = 768;  N = 768;  tt = b - 432;  nt = 12; }
  else if (b < 1152) { in = W1   + (size_t)l * 768 * 3072; out = w1T   + (size_t)l * 3072 * 768; K = 768;  N = 3072; tt = b - 576;  nt = 48; }
  else               { in = W2   + (size_t)l * 3072 * 768; out = w2T   + (size_t)l * 768 * 3072; K = 3072; N = 768;  tt = b - 1152; nt = 12; }
  transpose_tile(in, out, K, N, tt, nt, tid, t);
}

// ---------------- GEMM (proven round-8 structure, BK=64 as 2x32 subtiles):
// C = A[M,K](bf16) @ Bt[N,K]^T + bias. EPI 0: bias->bf16; 1: bias+gelu->bf16
template <int BM, int EPI>
__global__ __launch_bounds__(256) void gemm_bt(
    const short* __restrict__ A, const short* __restrict__ Bt,
    const float* __restrict__ bias, const float* __restrict__ resid,
    void* __restrict__ Cout, int M, int Nn, int K)
{
  constexpr int AW = BM / 64;
  constexpr int MI = BM / 32;
  __shared__ short As[2 * BM * 32];
  __shared__ short Bs[2 * 128 * 32];
  const int tid = threadIdx.x, lane = tid & 63, w = tid >> 6;
  const int wr = w >> 1, wc = w & 1;
  const int l15 = lane & 15, l4 = lane >> 4;
  const int m0 = blockIdx.y * BM, n0 = blockIdx.x * 128;
  const int crow = lane >> 2, ccol = (lane & 3) * 8;

  f32x4 acc[MI][4] = {};

  for (int k0 = 0; k0 < K; k0 += 64) {
    #pragma unroll
    for (int ks = 0; ks < 2; ++ks) {
      #pragma unroll
      for (int s = 0; s < AW; ++s) {
        int c = w * AW + s;
        gload16(A + (size_t)(m0 + c * 16 + crow) * K + k0 + ks * 32 + ccol,
                &As[ks * BM * 32 + c * 512]);
      }
      #pragma unroll
      for (int s = 0; s < 2; ++s) {
        int c = w * 2 + s;
        gload16(Bt + (size_t)(n0 + c * 16 + crow) * K + k0 + ks * 32 + ccol,
                &Bs[ks * 128 * 32 + c * 512]);
      }
    }
    __syncthreads();

    #pragma unroll
    for (int ks = 0; ks < 2; ++ks) {
      short8 af[MI], bfr[4];
      #pragma unroll
      for (int i = 0; i < MI; ++i)
        af[i] = *reinterpret_cast<const short8*>(
            &As[ks * BM * 32 + (wr * (BM / 2) + i * 16 + l15) * 32 + l4 * 8]);
      #pragma unroll
      for (int j = 0; j < 4; ++j)
        bfr[j] = *reinterpret_cast<const short8*>(
            &Bs[ks * 128 * 32 + (wc * 64 + j * 16 + l15) * 32 + l4 * 8]);
      #pragma unroll
      for (int i = 0; i < MI; ++i)
        #pragma unroll
        for (int j = 0; j < 4; ++j)
          acc[i][j] = __builtin_amdgcn_mfma_f32_16x16x32_bf16(af[i], bfr[j], acc[i][j], 0, 0, 0);
    }
    __syncthreads();
  }

  #pragma unroll
  for (int i = 0; i < MI; ++i) {
    #pragma unroll
    for (int j = 0; j < 4; ++j) {
      #pragma unroll
      for (int r = 0; r < 4; ++r) {
        int row = m0 + wr * (BM / 2) + i * 16 + l4 * 4 + r;
        int col = n0 + wc * 64 + j * 16 + l15;
        float v = acc[i][j][r] + bias[col];
        if constexpr (EPI == 1) v = 0.5f * v * (1.0f + erf_fast(v * 0.70710678118654752f));
        ((short*)Cout)[(size_t)row * Nn + col] = f2bf(v);
      }
    }
  }
}

// ---------------- split-K GEMM (BK=64, 4-way): bf16 partials, z in {0..3}
__global__ __launch_bounds__(256) void gemm_sk(
    const short* __restrict__ A, const short* __restrict__ Bt,
    short* __restrict__ p0, short* __restrict__ p1,
    short* __restrict__ p2, short* __restrict__ p3,
    int M, int Nn, int Kstride, int Klen)
{
  __shared__ short As[2 * 128 * 32];
  __shared__ short Bs[2 * 128 * 32];
  const int tid = threadIdx.x, lane = tid & 63, w = tid >> 6;
  const int wr = w >> 1, wc = w & 1;
  const int l15 = lane & 15, l4 = lane >> 4;
  const int m0 = blockIdx.y * 128, n0 = blockIdx.x * 128;
  const int koff = blockIdx.z * Klen;
  const int crow = lane >> 2, ccol = (lane & 3) * 8;

  f32x4 acc[4][4] = {};

  for (int k0 = 0; k0 < Klen; k0 += 64) {
    #pragma unroll
    for (int ks = 0; ks < 2; ++ks) {
      #pragma unroll
      for (int s = 0; s < 2; ++s) {
        int c = w * 2 + s;
        gload16(A + (size_t)(m0 + c * 16 + crow) * Kstride + koff + k0 + ks * 32 + ccol,
                &As[ks * 4096 + c * 512]);
      }
      #pragma unroll
      for (int s = 0; s < 2; ++s) {
        int c = w * 2 + s;
        gload16(Bt + (size_t)(n0 + c * 16 + crow) * Kstride + koff + k0 + ks * 32 + ccol,
                &Bs[ks * 4096 + c * 512]);
      }
    }
    __syncthreads();

    #pragma unroll
    for (int ks = 0; ks < 2; ++ks) {
      short8 af[4], bfr[4];
      #pragma unroll
      for (int i = 0; i < 4; ++i)
        af[i] = *reinterpret_cast<const short8*>(
            &As[ks * 4096 + (wr * 64 + i * 16 + l15) * 32 + l4 * 8]);
      #pragma unroll
      for (int j = 0; j < 4; ++j)
        bfr[j] = *reinterpret_cast<const short8*>(
            &Bs[ks * 4096 + (wc * 64 + j * 16 + l15) * 32 + l4 * 8]);
      #pragma unroll
      for (int i = 0; i < 4; ++i)
        #pragma unroll
        for (int j = 0; j < 4; ++j)
          acc[i][j] = __builtin_amdgcn_mfma_f32_16x16x32_bf16(af[i], bfr[j], acc[i][j], 0, 0, 0);
    }
    __syncthreads();
  }

  short* P = (blockIdx.z == 0) ? p0 : (blockIdx.z == 1) ? p1 : (blockIdx.z == 2) ? p2 : p3;
  #pragma unroll
  for (int i = 0; i < 4; ++i)
    #pragma unroll
    for (int j = 0; j < 4; ++j)
      #pragma unroll
      for (int r = 0; r < 4; ++r) {
        int row = m0 + wr * 64 + i * 16 + l4 * 4 + r;
        int col = n0 + wc * 64 + j * 16 + l15;
        P[(size_t)row * Nn + col] = f2bf(acc[i][j][r]);
      }
}

// ---------------- Flash attention (round-8 proven form, KVBLK=64)
__global__ __launch_bounds__(256) void attn_k(
    const short* __restrict__ qkv, const int* __restrict__ amask,
    short* __restrict__ out)
{
  __shared__ short Kl[64][72];
  __shared__ short Vt[64][68];
  __shared__ short Pl[4][16][72];
  const int b = blockIdx.z, h = blockIdx.y, qt = blockIdx.x;
  const int tid = threadIdx.x, lane = tid & 63, w = tid >> 6;
  const int l15 = lane & 15, l4 = lane >> 4;
  const int tok0 = b * 512;
  const int q0 = qt * 64 + w * 16;

  short8 qf[2];
  #pragma unroll
  for (int kk = 0; kk < 2; ++kk)
    qf[kk] = *reinterpret_cast<const short8*>(
        qkv + (size_t)(tok0 + q0 + l15) * 2304 + h * 64 + kk * 32 + l4 * 8);

  f32x4 oacc[4] = {};
  float mrow[4], lrow[4];
  #pragma unroll
  for (int r = 0; r < 4; ++r) { mrow[r] = -1e30f; lrow[r] = 0.f; }

  for (int kt0 = 0; kt0 < 512; kt0 += 64) {
    #pragma unroll
    for (int i = 0; i < 2; ++i) {
      int c = tid + i * 256;
      int r = c >> 3, dc = c & 7;
      short8 v = *reinterpret_cast<const short8*>(
          qkv + (size_t)(tok0 + kt0 + r) * 2304 + 768 + h * 64 + dc * 8);
      *reinterpret_cast<short8*>(&Kl[r][dc * 8]) = v;
    }
    #pragma unroll
    for (int i = 0; i < 2; ++i) {
      int c = tid + i * 256;
      int r = c >> 3, dc = c & 7;
      short8 v = *reinterpret_cast<const short8*>(
          qkv + (size_t)(tok0 + kt0 + r) * 2304 + 1536 + h * 64 + dc * 8);
      #pragma unroll
      for (int j = 0; j < 8; ++j) Vt[dc * 8 + j][r] = v[j];
    }
    __syncthreads();

    f32x4 sacc[4] = {};
    #pragma unroll
    for (int t = 0; t < 4; ++t) {
      #pragma unroll
      for (int kk = 0; kk < 2; ++kk) {
        short8 kf = *reinterpret_cast<const short8*>(&Kl[t * 16 + l15][kk * 32 + l4 * 8]);
        sacc[t] = __builtin_amdgcn_mfma_f32_16x16x32_bf16(qf[kk], kf, sacc[t], 0, 0, 0);
      }
    }
    float p[4][4];
    #pragma unroll
    for (int t = 0; t < 4; ++t) {
      int ktok = kt0 + t * 16 + l15;
      float biasv = amask[b * 512 + ktok] ? 0.f : -1e9f;
      #pragma unroll
      for (int r = 0; r < 4; ++r) p[t][r] = sacc[t][r] * 0.125f + biasv;
    }
    #pragma unroll
    for (int r = 0; r < 4; ++r) {
      float mx = fmaxf(fmaxf(p[0][r], p[1][r]), fmaxf(p[2][r], p[3][r]));
      #pragma unroll
      for (int s = 1; s <= 8; s <<= 1) mx = fmaxf(mx, __shfl_xor(mx, s, 64));
      float mnew = fmaxf(mrow[r], mx);
      float alpha = __expf(mrow[r] - mnew);
      mrow[r] = mnew;
      float sum = 0.f;
      #pragma unroll
      for (int t = 0; t < 4; ++t) { p[t][r] = __expf(p[t][r] - mnew); sum += p[t][r]; }
      #pragma unroll
      for (int s = 1; s <= 8; s <<= 1) sum += __shfl_xor(sum, s, 64);
      lrow[r] = lrow[r] * alpha + sum;
      #pragma unroll
      for (int t = 0; t < 4; ++t) oacc[t][r] *= alpha;
    }
    #pragma unroll
    for (int t = 0; t < 4; ++t)
      #pragma unroll
      for (int r = 0; r < 4; ++r)
        Pl[w][l4 * 4 + r][t * 16 + l15] = f2bf(p[t][r]);
    #pragma unroll
    for (int kk = 0; kk < 2; ++kk) {
      short8 pf = *reinterpret_cast<const short8*>(&Pl[w][l15][kk * 32 + l4 * 8]);
      #pragma unroll
      for (int t = 0; t < 4; ++t) {
        const unsigned* vp = reinterpret_cast<const unsigned*>(&Vt[t * 16 + l15][0]);
        union { short8 s; unsigned u[4]; } vu;
        #pragma unroll
        for (int w2 = 0; w2 < 4; ++w2) vu.u[w2] = vp[kk * 16 + l4 * 4 + w2];
        oacc[t] = __builtin_amdgcn_mfma_f32_16x16x32_bf16(pf, vu.s, oacc[t], 0, 0, 0);
      }
    }
    __syncthreads();
  }

  #pragma unroll
  for (int t = 0; t < 4; ++t)
    #pragma unroll
    for (int r = 0; r < 4; ++r) {
      int tok = tok0 + q0 + l4 * 4 + r;
      int dh = t * 16 + l15;
      out[(size_t)tok * 768 + h * 64 + dh] = f2bf(oacc[t][r] / lrow[r]);
    }
}

// ---------------- LN of (p0+p1+p2+p3 + bias + resid): wave-per-token, 4 tok/block
__global__ __launch_bounds__(256) void ln2_k(
    const short* __restrict__ p0, const short* __restrict__ p1,
    const short* __restrict__ p2, const short* __restrict__ p3,
    const float* __restrict__ bias, const float* __restrict__ resid,
    const float* __restrict__ g, const float* __restrict__ be,
    float* __restrict__ xf, short* __restrict__ xb)
{
  const int w = threadIdx.x >> 6, lane = threadIdx.x & 63;
  const int t = blockIdx.x * 4 + w;
  const size_t base = (size_t)t * 768;
  float2 v[6];
  float s = 0.f, ss = 0.f;
  #pragma unroll
  for (int e = 0; e < 6; ++e) {
    int c = e * 128 + lane * 2;
    unsigned a0 = *reinterpret_cast<const unsigned*>(p0 + base + c);
    unsigned a1 = *reinterpret_cast<const unsigned*>(p1 + base + c);
    unsigned a2 = *reinterpret_cast<const unsigned*>(p2 + base + c);
    unsigned a3 = *reinterpret_cast<const unsigned*>(p3 + base + c);
    float2 r = *reinterpret_cast<const float2*>(resid + base + c);
    float2 bb = *reinterpret_cast<const float2*>(bias + c);
    float vx = (bf2f((short)a0) + bf2f((short)a1))
             + (bf2f((short)a2) + bf2f((short)a3)) + bb.x + r.x;
    float vy = (bf2f((short)(a0 >> 16)) + bf2f((short)(a1 >> 16)))
             + (bf2f((short)(a2 >> 16)) + bf2f((short)(a3 >> 16))) + bb.y + r.y;
    v[e].x = vx; v[e].y = vy;
    s += vx + vy; ss += vx * vx + vy * vy;
  }
  #pragma unroll
  for (int m = 1; m <= 32; m <<= 1) { s += __shfl_xor(s, m, 64); ss += __shfl_xor(ss, m, 64); }
  float mean = s * (1.f / 768.f);
  float var = ss * (1.f / 768.f) - mean * mean;
  float rs = rsqrtf(var + 1e-12f);
  #pragma unroll
  for (int e = 0; e < 6; ++e) {
    int c = e * 128 + lane * 2;
    float2 gg = *reinterpret_cast<const float2*>(g + c);
    float2 bn = *reinterpret_cast<const float2*>(be + c);
    float ox = (v[e].x - mean) * rs * gg.x + bn.x;
    float oy = (v[e].y - mean) * rs * gg.y + bn.y;
    *reinterpret_cast<float2*>(xf + base + c) = make_float2(ox, oy);
    *reinterpret_cast<unsigned*>(xb + base + c) = pack2bf(ox, oy);
  }
}

// ---------------- embedding + LN: wave-per-token, 4 tok/block
__global__ __launch_bounds__(256) void embed_ln_k(
    const int* __restrict__ ids, const float* __restrict__ tok_emb,
    const float* __restrict__ pos_emb, const float* __restrict__ g,
    const float* __restrict__ be, float* __restrict__ xf, short* __restrict__ xb)
{
  const int w = threadIdx.x >> 6, lane = threadIdx.x & 63;
  const int t = blockIdx.x * 4 + w;
  const size_t base = (size_t)t * 768;
  const int id = ids[t], sp = t & 511;
  float2 v[6];
  float s = 0.f, ss = 0.f;
  #pragma unroll
  for (int e = 0; e < 6; ++e) {
    int c = e * 128 + lane * 2;
    float2 te = *reinterpret_cast<const float2*>(tok_emb + (size_t)id * 768 + c);
    float2 pe = *reinterpret_cast<const float2*>(pos_emb + (size_t)sp * 768 + c);
    float vx = te.x + pe.x, vy = te.y + pe.y;
    v[e].x = vx; v[e].y = vy;
    s += vx + vy; ss += vx * vx + vy * vy;
  }
  #pragma unroll
  for (int m = 1; m <= 32; m <<= 1) { s += __shfl_xor(s, m, 64); ss += __shfl_xor(ss, m, 64); }
  float mean = s * (1.f / 768.f);
  float var = ss * (1.f / 768.f) - mean * mean;
  float rs = rsqrtf(var + 1e-12f);
  #pragma unroll
  for (int e = 0; e < 6; ++e) {
    int c = e * 128 + lane * 2;
    float2 gg = *reinterpret_cast<const float2*>(g + c);
    float2 bn = *reinterpret_cast<const float2*>(be + c);
    float ox = (v[e].x - mean) * rs * gg.x + bn.x;
    float oy = (v[e].y - mean) * rs * gg.y + bn.y;
    *reinterpret_cast<float2*>(xf + base + c) = make_float2(ox, oy);
    *reinterpret_cast<unsigned*>(xb + base + c) = pack2bf(ox, oy);
  }
}

// ---------------- gather/scatter (parallel): cls + sentinel rows -> out[8][64][768]
__global__ __launch_bounds__(512) void gather_k(
    const int* __restrict__ ids, const float* __restrict__ x, float* __restrict__ out)
{
  const int doc = blockIdx.x, tid = threadIdx.x;
  const int lane = tid & 63, w = tid >> 6;
  __shared__ int src[64];
  __shared__ int wave_sent[8];
  __shared__ int cls_pos;
  if (tid < 64) src[tid] = -1;
  if (tid == 0) cls_pos = 0x7fffffff;
  __syncthreads();

  const int id = ids[doc * 512 + tid];
  const bool is_sent = (id == 103);
  const unsigned long long m = __ballot(is_sent);
  if (lane == 0) wave_sent[w] = __popcll(m);
  if (id == 102) atomicMin(&cls_pos, tid);
  __syncthreads();

  int total = 0, prefix = 0;
  #pragma unroll
  for (int i = 0; i < 8; ++i) {
    int c = wave_sent[i];
    if (i < w) prefix += c;
    total += c;
  }
  if (is_sent) {
    unsigned long long lt = lane ? (~0ULL >> (64 - lane)) : 0ULL;
    int d = 1 + prefix + __popcll(m & lt);
    if (d < total && d < 64) src[d] = tid;
  }
  if (tid == 0 && total > 0 && cls_pos != 0x7fffffff) src[0] = cls_pos;
  __syncthreads();

  for (int i = tid; i < 64 * 192; i += 512) {
    int row = i / 192, c4 = i - row * 192;
    int sp = src[row];
    float4 v = make_float4(0.f, 0.f, 0.f, 0.f);
    if (sp >= 0)
      v = reinterpret_cast<const float4*>(x + (size_t)(doc * 512 + sp) * 768)[c4];
    reinterpret_cast<float4*>(out + (size_t)doc * 64 * 768)[i] = v;
  }
}

extern "C" void kernel_launch(void* const* d_in, const int* in_sizes, int n_in,
                              void* d_out, int out_size, void* d_ws, size_t ws_size,
                              hipStream_t stream)
{
  const int* ids = (const int*)d_in[0];
  const int* am = (const int*)d_in[1];
  const float* tok_emb = (const float*)d_in[2];
  const float* pos_emb = (const float*)d_in[3];
  const float* eg = (const float*)d_in[4];
  const float* eb = (const float*)d_in[5];
  const float* Wqkv = (const float*)d_in[6];
  const float* bqkv = (const float*)d_in[7];
  const float* Wo = (const float*)d_in[8];
  const float* bo = (const float*)d_in[9];
  const float* g1 = (const float*)d_in[10];
  const float* b1n = (const float*)d_in[11];
  const float* W1 = (const float*)d_in[12];
  const float* b1f = (const float*)d_in[13];
  const float* W2 = (const float*)d_in[14];
  const float* b2f = (const float*)d_in[15];
  const float* g2 = (const float*)d_in[16];
  const float* b2n = (const float*)d_in[17];

  char* ws = (char*)d_ws;
  float* x_f   = (float*)(ws);                  // residual stream (f32)
  short* x_b   = (short*)(ws + 12582912);       // residual (bf16)
  float* x2_f  = (float*)(ws + 18874368);       // post-LN1 (f32)
  short* x2_b  = (short*)(ws + 31457280);       // post-LN1 (bf16)
  short* pp0   = (short*)(ws + 37748736);       // split-K partial 0
  short* pp1   = (short*)(ws + 37748736 + 6291456);
  short* qkv   = (short*)(ws + 50331648);       // QKV (bf16, 18.9MB)
  short* pp2   = (short*)(ws + 50331648);       // partial 2 (aliases dead qkv)
  short* pp3   = (short*)(ws + 50331648 + 6291456);
  short* attn  = (short*)(ws + 69206016);       // attn out
  short* hb    = (short*)(ws + 75497472);       // FFN1 out (25MB)
  const size_t WQ = 2304ull * 768, WO = 768ull * 768, W1S = 3072ull * 768, W2S = 768ull * 3072;
  const size_t NEED_ALL = 100663296ull + 12ull * (WQ + WO + W1S + W2S) * 2ull; // ~258 MB
  const bool big = ws_size >= NEED_ALL;

  short* wqkvT = (short*)(ws + 100663296);
  short* woT, *w1T, *w2T;
  if (big) {
    woT = wqkvT + 12 * WQ;
    w1T = woT + 12 * WO;
    w2T = w1T + 12 * W1S;
  } else {
    woT = (short*)(ws + 104202240);
    w1T = (short*)(ws + 105381888);
    w2T = (short*)(ws + 110100480);
  }

  embed_ln_k<<<1024, 256, 0, stream>>>(ids, tok_emb, pos_emb, eg, eb, x_f, x_b);

  if (big)
    transpose12_k<<<dim3(1728, 1, 12), 256, 0, stream>>>(
        Wqkv, Wo, W1, W2, wqkvT, woT, w1T, w2T);

  for (int l = 0; l < 12; ++l) {
    short *wq, *wo, *w1, *w2;
    if (big) {
      wq = wqkvT + l * WQ; wo = woT + l * WO; w1 = w1T + l * W1S; w2 = w2T + l * W2S;
    } else {
      transpose_all_k<<<1728, 256, 0, stream>>>(
          Wqkv + (size_t)l * 768 * 2304, Wo + (size_t)l * 768 * 768,
          W1 + (size_t)l * 768 * 3072, W2 + (size_t)l * 3072 * 768,
          wqkvT, woT, w1T, w2T);
      wq = wqkvT; wo = woT; w1 = w1T; w2 = w2T;
    }

    gemm_bt<128, 0><<<dim3(18, 32), 256, 0, stream>>>(
        x_b, wq, bqkv + (size_t)l * 2304, nullptr, qkv, 4096, 2304, 768);
    attn_k<<<dim3(8, 12, 8), 256, 0, stream>>>(qkv, am, attn);

    gemm_sk<<<dim3(6, 32, 4), 256, 0, stream>>>(
        attn, wo, pp0, pp1, pp2, pp3, 4096, 768, 768, 192);
    ln2_k<<<1024, 256, 0, stream>>>(
        pp0, pp1, pp2, pp3, bo + (size_t)l * 768, x_f,
        g1 + (size_t)l * 768, b1n + (size_t)l * 768, x2_f, x2_b);

    gemm_bt<128, 1><<<dim3(24, 32), 256, 0, stream>>>(
        x2_b, w1, b1f + (size_t)l * 3072, nullptr, hb, 4096, 3072, 768);

    gemm_sk<<<dim3(6, 32, 4), 256, 0, stream>>>(
        hb, w2, pp0, pp1, pp2, pp3, 4096, 768, 3072, 768);
    ln2_k<<<1024, 256, 0, stream>>>(
        pp0, pp1, pp2, pp3, b2f + (size_t)l * 768, x2_f,
        g2 + (size_t)l * 768, b2n + (size_t)l * 768, x_f, x_b);
  }

  gather_k<<<8, 512, 0, stream>>>(ids, x_f, (float*)d_out);
}

// Round 12
// 2302.610 us; speedup vs baseline: 1.0282x; 1.0187x over previous
//
#include <hip/hip_runtime.h>
#include <hip/hip_bf16.h>

#define DEV static __device__ __forceinline__

using short8 = __attribute__((ext_vector_type(8))) short;
using f32x4 = __attribute__((ext_vector_type(4))) float;

DEV short f2bf(float f) {
  union { float f; unsigned u; } x; x.f = f;
  unsigned r = x.u + 0x7fffu + ((x.u >> 16) & 1u);
  return (short)(r >> 16);
}

DEV float bf2f(short s) {
  union { unsigned u; float f; } x; x.u = ((unsigned)(unsigned short)s) << 16;
  return x.f;
}

DEV void gload16(const void* g, void* lds) {
  __builtin_amdgcn_global_load_lds(
      (const __attribute__((address_space(1))) void*)g,
      (__attribute__((address_space(3))) void*)lds, 16, 0, 0);
}

// Abramowitz-Stegun 7.1.26 erf, |err| <= 1.5e-7
DEV float erf_fast(float x) {
  float ax = fabsf(x);
  float t = __fdividef(1.f, 1.f + 0.3275911f * ax);
  float y = t * (0.254829592f + t * (-0.284496736f +
            t * (1.421413741f + t * (-1.453152027f + t * 1.061405429f))));
  float r = 1.f - y * __expf(-ax * ax);
  return copysignf(r, x);
}

// ---------------- merged per-layer weight transpose: f32 [K][N] -> bf16 [N][K]
// stride 76: 4-way read conflicts (was 8-way at 72)
__global__ __launch_bounds__(256) void transpose_all_k(
    const float* __restrict__ Wqkv, const float* __restrict__ Wo,
    const float* __restrict__ W1, const float* __restrict__ W2,
    short* __restrict__ wqkvT, short* __restrict__ woT,
    short* __restrict__ w1T, short* __restrict__ w2T)
{
  __shared__ short t[64][76];
  const int b = blockIdx.x, tid = threadIdx.x;
  const float* in; short* out; int K, N, tt, nt;
  if (b < 432)       { in = Wqkv; out = wqkvT; K = 768;  N = 2304; tt = b;        nt = 36; }
  else if (b < 576)  { in = Wo;   out = woT;   K = 768;  N = 768;  tt = b - 432;  nt = 12; }
  else if (b < 1152) { in = W1;   out = w1T;   K = 768;  N = 3072; tt = b - 576;  nt = 48; }
  else               { in = W2;   out = w2T;   K = 3072; N = 768;  tt = b - 1152; nt = 12; }
  const int n0 = (tt % nt) * 64, k0 = (tt / nt) * 64;
  #pragma unroll
  for (int p = 0; p < 4; ++p) {
    int r = p * 16 + (tid >> 4), c4 = tid & 15;
    float4 v = *reinterpret_cast<const float4*>(in + (size_t)(k0 + r) * N + n0 + c4 * 4);
    t[r][c4 * 4 + 0] = f2bf(v.x);
    t[r][c4 * 4 + 1] = f2bf(v.y);
    t[r][c4 * 4 + 2] = f2bf(v.z);
    t[r][c4 * 4 + 3] = f2bf(v.w);
  }
  __syncthreads();
  #pragma unroll
  for (int q = 0; q < 2; ++q) {
    int n = tid >> 2, kc = (tid & 3) + q * 4;
    short8 o;
    #pragma unroll
    for (int j = 0; j < 8; ++j) o[j] = t[kc * 8 + j][n];
    *reinterpret_cast<short8*>(out + (size_t)(n0 + n) * K + k0 + kc * 8) = o;
  }
}

// ---------------- GEMM (round-8 proven structure, BK=64 as 2x32 subtiles):
// C = A[M,K](bf16) @ Bt[N,K]^T + bias. EPI 0: bias->bf16; 1: bias+gelu->bf16
template <int BM, int EPI>
__global__ __launch_bounds__(256) void gemm_bt(
    const short* __restrict__ A, const short* __restrict__ Bt,
    const float* __restrict__ bias,
    void* __restrict__ Cout, int M, int Nn, int K)
{
  constexpr int AW = BM / 64;
  constexpr int MI = BM / 32;
  __shared__ short As[2 * BM * 32];
  __shared__ short Bs[2 * 128 * 32];
  const int tid = threadIdx.x, lane = tid & 63, w = tid >> 6;
  const int wr = w >> 1, wc = w & 1;
  const int l15 = lane & 15, l4 = lane >> 4;
  const int m0 = blockIdx.y * BM, n0 = blockIdx.x * 128;
  const int crow = lane >> 2, ccol = (lane & 3) * 8;

  f32x4 acc[MI][4] = {};

  for (int k0 = 0; k0 < K; k0 += 64) {
    #pragma unroll
    for (int ks = 0; ks < 2; ++ks) {
      #pragma unroll
      for (int s = 0; s < AW; ++s) {
        int c = w * AW + s;
        gload16(A + (size_t)(m0 + c * 16 + crow) * K + k0 + ks * 32 + ccol,
                &As[ks * BM * 32 + c * 512]);
      }
      #pragma unroll
      for (int s = 0; s < 2; ++s) {
        int c = w * 2 + s;
        gload16(Bt + (size_t)(n0 + c * 16 + crow) * K + k0 + ks * 32 + ccol,
                &Bs[ks * 128 * 32 + c * 512]);
      }
    }
    __syncthreads();

    #pragma unroll
    for (int ks = 0; ks < 2; ++ks) {
      short8 af[MI], bfr[4];
      #pragma unroll
      for (int i = 0; i < MI; ++i)
        af[i] = *reinterpret_cast<const short8*>(
            &As[ks * BM * 32 + (wr * (BM / 2) + i * 16 + l15) * 32 + l4 * 8]);
      #pragma unroll
      for (int j = 0; j < 4; ++j)
        bfr[j] = *reinterpret_cast<const short8*>(
            &Bs[ks * 128 * 32 + (wc * 64 + j * 16 + l15) * 32 + l4 * 8]);
      #pragma unroll
      for (int i = 0; i < MI; ++i)
        #pragma unroll
        for (int j = 0; j < 4; ++j)
          acc[i][j] = __builtin_amdgcn_mfma_f32_16x16x32_bf16(af[i], bfr[j], acc[i][j], 0, 0, 0);
    }
    __syncthreads();
  }

  #pragma unroll
  for (int i = 0; i < MI; ++i) {
    #pragma unroll
    for (int j = 0; j < 4; ++j) {
      #pragma unroll
      for (int r = 0; r < 4; ++r) {
        int row = m0 + wr * (BM / 2) + i * 16 + l4 * 4 + r;
        int col = n0 + wc * 64 + j * 16 + l15;
        float v = acc[i][j][r] + bias[col];
        if constexpr (EPI == 1) v = 0.5f * v * (1.0f + erf_fast(v * 0.70710678118654752f));
        ((short*)Cout)[(size_t)row * Nn + col] = f2bf(v);
      }
    }
  }
}

// ---------------- split-K GEMM (BK=64, 4-way): bf16 partials, z in {0..3}
__global__ __launch_bounds__(256) void gemm_sk(
    const short* __restrict__ A, const short* __restrict__ Bt,
    short* __restrict__ p0, short* __restrict__ p1,
    short* __restrict__ p2, short* __restrict__ p3,
    int M, int Nn, int Kstride, int Klen)
{
  __shared__ short As[2 * 128 * 32];
  __shared__ short Bs[2 * 128 * 32];
  const int tid = threadIdx.x, lane = tid & 63, w = tid >> 6;
  const int wr = w >> 1, wc = w & 1;
  const int l15 = lane & 15, l4 = lane >> 4;
  const int m0 = blockIdx.y * 128, n0 = blockIdx.x * 128;
  const int koff = blockIdx.z * Klen;
  const int crow = lane >> 2, ccol = (lane & 3) * 8;

  f32x4 acc[4][4] = {};

  for (int k0 = 0; k0 < Klen; k0 += 64) {
    #pragma unroll
    for (int ks = 0; ks < 2; ++ks) {
      #pragma unroll
      for (int s = 0; s < 2; ++s) {
        int c = w * 2 + s;
        gload16(A + (size_t)(m0 + c * 16 + crow) * Kstride + koff + k0 + ks * 32 + ccol,
                &As[ks * 4096 + c * 512]);
      }
      #pragma unroll
      for (int s = 0; s < 2; ++s) {
        int c = w * 2 + s;
        gload16(Bt + (size_t)(n0 + c * 16 + crow) * Kstride + koff + k0 + ks * 32 + ccol,
                &Bs[ks * 4096 + c * 512]);
      }
    }
    __syncthreads();

    #pragma unroll
    for (int ks = 0; ks < 2; ++ks) {
      short8 af[4], bfr[4];
      #pragma unroll
      for (int i = 0; i < 4; ++i)
        af[i] = *reinterpret_cast<const short8*>(
            &As[ks * 4096 + (wr * 64 + i * 16 + l15) * 32 + l4 * 8]);
      #pragma unroll
      for (int j = 0; j < 4; ++j)
        bfr[j] = *reinterpret_cast<const short8*>(
            &Bs[ks * 4096 + (wc * 64 + j * 16 + l15) * 32 + l4 * 8]);
      #pragma unroll
      for (int i = 0; i < 4; ++i)
        #pragma unroll
        for (int j = 0; j < 4; ++j)
          acc[i][j] = __builtin_amdgcn_mfma_f32_16x16x32_bf16(af[i], bfr[j], acc[i][j], 0, 0, 0);
    }
    __syncthreads();
  }

  short* P = (blockIdx.z == 0) ? p0 : (blockIdx.z == 1) ? p1 : (blockIdx.z == 2) ? p2 : p3;
  #pragma unroll
  for (int i = 0; i < 4; ++i)
    #pragma unroll
    for (int j = 0; j < 4; ++j)
      #pragma unroll
      for (int r = 0; r < 4; ++r) {
        int row = m0 + wr * 64 + i * 16 + l4 * 4 + r;
        int col = n0 + wc * 64 + j * 16 + l15;
        P[(size_t)row * Nn + col] = f2bf(acc[i][j][r]);
      }
}

// ---------------- Flash attention (round-8 proven form, KVBLK=64)
__global__ __launch_bounds__(256) void attn_k(
    const short* __restrict__ qkv, const int* __restrict__ amask,
    short* __restrict__ out)
{
  __shared__ short Kl[64][72];
  __shared__ short Vt[64][68];
  __shared__ short Pl[4][16][72];
  const int b = blockIdx.z, h = blockIdx.y, qt = blockIdx.x;
  const int tid = threadIdx.x, lane = tid & 63, w = tid >> 6;
  const int l15 = lane & 15, l4 = lane >> 4;
  const int tok0 = b * 512;
  const int q0 = qt * 64 + w * 16;

  short8 qf[2];
  #pragma unroll
  for (int kk = 0; kk < 2; ++kk)
    qf[kk] = *reinterpret_cast<const short8*>(
        qkv + (size_t)(tok0 + q0 + l15) * 2304 + h * 64 + kk * 32 + l4 * 8);

  f32x4 oacc[4] = {};
  float mrow[4], lrow[4];
  #pragma unroll
  for (int r = 0; r < 4; ++r) { mrow[r] = -1e30f; lrow[r] = 0.f; }

  for (int kt0 = 0; kt0 < 512; kt0 += 64) {
    #pragma unroll
    for (int i = 0; i < 2; ++i) {
      int c = tid + i * 256;
      int r = c >> 3, dc = c & 7;
      short8 v = *reinterpret_cast<const short8*>(
          qkv + (size_t)(tok0 + kt0 + r) * 2304 + 768 + h * 64 + dc * 8);
      *reinterpret_cast<short8*>(&Kl[r][dc * 8]) = v;
    }
    #pragma unroll
    for (int i = 0; i < 2; ++i) {
      int c = tid + i * 256;
      int r = c >> 3, dc = c & 7;
      short8 v = *reinterpret_cast<const short8*>(
          qkv + (size_t)(tok0 + kt0 + r) * 2304 + 1536 + h * 64 + dc * 8);
      #pragma unroll
      for (int j = 0; j < 8; ++j) Vt[dc * 8 + j][r] = v[j];
    }
    __syncthreads();

    f32x4 sacc[4] = {};
    #pragma unroll
    for (int t = 0; t < 4; ++t) {
      #pragma unroll
      for (int kk = 0; kk < 2; ++kk) {
        short8 kf = *reinterpret_cast<const short8*>(&Kl[t * 16 + l15][kk * 32 + l4 * 8]);
        sacc[t] = __builtin_amdgcn_mfma_f32_16x16x32_bf16(qf[kk], kf, sacc[t], 0, 0, 0);
      }
    }
    float p[4][4];
    #pragma unroll
    for (int t = 0; t < 4; ++t) {
      int ktok = kt0 + t * 16 + l15;
      float biasv = amask[b * 512 + ktok] ? 0.f : -1e9f;
      #pragma unroll
      for (int r = 0; r < 4; ++r) p[t][r] = sacc[t][r] * 0.125f + biasv;
    }
    #pragma unroll
    for (int r = 0; r < 4; ++r) {
      float mx = fmaxf(fmaxf(p[0][r], p[1][r]), fmaxf(p[2][r], p[3][r]));
      #pragma unroll
      for (int s = 1; s <= 8; s <<= 1) mx = fmaxf(mx, __shfl_xor(mx, s, 64));
      float mnew = fmaxf(mrow[r], mx);
      float alpha = __expf(mrow[r] - mnew);
      mrow[r] = mnew;
      float sum = 0.f;
      #pragma unroll
      for (int t = 0; t < 4; ++t) { p[t][r] = __expf(p[t][r] - mnew); sum += p[t][r]; }
      #pragma unroll
      for (int s = 1; s <= 8; s <<= 1) sum += __shfl_xor(sum, s, 64);
      lrow[r] = lrow[r] * alpha + sum;
      #pragma unroll
      for (int t = 0; t < 4; ++t) oacc[t][r] *= alpha;
    }
    // P -> per-wave LDS (wave-private: compiler's wave-local lgkmcnt orders it)
    #pragma unroll
    for (int t = 0; t < 4; ++t)
      #pragma unroll
      for (int r = 0; r < 4; ++r)
        Pl[w][l4 * 4 + r][t * 16 + l15] = f2bf(p[t][r]);
    #pragma unroll
    for (int kk = 0; kk < 2; ++kk) {
      short8 pf = *reinterpret_cast<const short8*>(&Pl[w][l15][kk * 32 + l4 * 8]);
      #pragma unroll
      for (int t = 0; t < 4; ++t) {
        const unsigned* vp = reinterpret_cast<const unsigned*>(&Vt[t * 16 + l15][0]);
        union { short8 s; unsigned u[4]; } vu;
        #pragma unroll
        for (int w2 = 0; w2 < 4; ++w2) vu.u[w2] = vp[kk * 16 + l4 * 4 + w2];
        oacc[t] = __builtin_amdgcn_mfma_f32_16x16x32_bf16(pf, vu.s, oacc[t], 0, 0, 0);
      }
    }
    __syncthreads();
  }

  #pragma unroll
  for (int t = 0; t < 4; ++t)
    #pragma unroll
    for (int r = 0; r < 4; ++r) {
      int tok = tok0 + q0 + l4 * 4 + r;
      int dh = t * 16 + l15;
      out[(size_t)tok * 768 + h * 64 + dh] = f2bf(oacc[t][r] / lrow[r]);
    }
}

// ---------------- LN of (p0+p1+p2+p3 + bias + resid): bf16 partials -> f32 + bf16 out
// (round-8 proven form)
__global__ __launch_bounds__(256) void ln2_k(
    const short* __restrict__ p0, const short* __restrict__ p1,
    const short* __restrict__ p2, const short* __restrict__ p3,
    const float* __restrict__ bias, const float* __restrict__ resid,
    const float* __restrict__ g, const float* __restrict__ be,
    float* __restrict__ xf, short* __restrict__ xb)
{
  const int t = blockIdx.x, tid = threadIdx.x;
  const size_t base = (size_t)t * 768;
  float v[3], s = 0.f, ss = 0.f;
  #pragma unroll
  for (int i = 0; i < 3; ++i) {
    int c = tid + i * 256;
    v[i] = (bf2f(p0[base + c]) + bf2f(p1[base + c]))
         + (bf2f(p2[base + c]) + bf2f(p3[base + c]))
         + bias[c] + resid[base + c];
    s += v[i]; ss += v[i] * v[i];
  }
  __shared__ float red[4][2];
  #pragma unroll
  for (int m = 1; m <= 32; m <<= 1) { s += __shfl_xor(s, m, 64); ss += __shfl_xor(ss, m, 64); }
  int w = tid >> 6;
  if ((tid & 63) == 0) { red[w][0] = s; red[w][1] = ss; }
  __syncthreads();
  s = red[0][0] + red[1][0] + red[2][0] + red[3][0];
  ss = red[0][1] + red[1][1] + red[2][1] + red[3][1];
  float mean = s * (1.f / 768.f);
  float var = ss * (1.f / 768.f) - mean * mean;
  float rs = rsqrtf(var + 1e-12f);
  #pragma unroll
  for (int i = 0; i < 3; ++i) {
    int c = tid + i * 256;
    float o = (v[i] - mean) * rs * g[c] + be[c];
    xf[base + c] = o;
    xb[base + c] = f2bf(o);
  }
}

// ---------------- embedding + LN (round-8 proven form)
__global__ __launch_bounds__(256) void embed_ln_k(
    const int* __restrict__ ids, const float* __restrict__ tok_emb,
    const float* __restrict__ pos_emb, const float* __restrict__ g,
    const float* __restrict__ be, float* __restrict__ xf, short* __restrict__ xb)
{
  const int t = blockIdx.x, tid = threadIdx.x;
  const int id = ids[t], sp = t & 511;
  float v[3], s = 0.f, ss = 0.f;
  #pragma unroll
  for (int i = 0; i < 3; ++i) {
    int c = tid + i * 256;
    v[i] = tok_emb[(size_t)id * 768 + c] + pos_emb[(size_t)sp * 768 + c];
    s += v[i]; ss += v[i] * v[i];
  }
  __shared__ float red[4][2];
  #pragma unroll
  for (int m = 1; m <= 32; m <<= 1) { s += __shfl_xor(s, m, 64); ss += __shfl_xor(ss, m, 64); }
  int w = tid >> 6;
  if ((tid & 63) == 0) { red[w][0] = s; red[w][1] = ss; }
  __syncthreads();
  s = red[0][0] + red[1][0] + red[2][0] + red[3][0];
  ss = red[0][1] + red[1][1] + red[2][1] + red[3][1];
  float mean = s * (1.f / 768.f);
  float var = ss * (1.f / 768.f) - mean * mean;
  float rs = rsqrtf(var + 1e-12f);
  #pragma unroll
  for (int i = 0; i < 3; ++i) {
    int c = tid + i * 256;
    float o = (v[i] - mean) * rs * g[c] + be[c];
    xf[(size_t)t * 768 + c] = o;
    xb[(size_t)t * 768 + c] = f2bf(o);
  }
}

// ---------------- gather/scatter (parallel): cls + sentinel rows -> out[8][64][768]
__global__ __launch_bounds__(512) void gather_k(
    const int* __restrict__ ids, const float* __restrict__ x, float* __restrict__ out)
{
  const int doc = blockIdx.x, tid = threadIdx.x;
  const int lane = tid & 63, w = tid >> 6;
  __shared__ int src[64];
  __shared__ int wave_sent[8];
  __shared__ int cls_pos;
  if (tid < 64) src[tid] = -1;
  if (tid == 0) cls_pos = 0x7fffffff;
  __syncthreads();

  const int id = ids[doc * 512 + tid];
  const bool is_sent = (id == 103);
  const unsigned long long m = __ballot(is_sent);
  if (lane == 0) wave_sent[w] = __popcll(m);
  if (id == 102) atomicMin(&cls_pos, tid);
  __syncthreads();

  int total = 0, prefix = 0;
  #pragma unroll
  for (int i = 0; i < 8; ++i) {
    int c = wave_sent[i];
    if (i < w) prefix += c;
    total += c;
  }
  if (is_sent) {
    unsigned long long lt = lane ? (~0ULL >> (64 - lane)) : 0ULL;
    int d = 1 + prefix + __popcll(m & lt);
    if (d < total && d < 64) src[d] = tid;
  }
  if (tid == 0 && total > 0 && cls_pos != 0x7fffffff) src[0] = cls_pos;
  __syncthreads();

  for (int i = tid; i < 64 * 192; i += 512) {
    int row = i / 192, c4 = i - row * 192;
    int sp = src[row];
    float4 v = make_float4(0.f, 0.f, 0.f, 0.f);
    if (sp >= 0)
      v = reinterpret_cast<const float4*>(x + (size_t)(doc * 512 + sp) * 768)[c4];
    reinterpret_cast<float4*>(out + (size_t)doc * 64 * 768)[i] = v;
  }
}

extern "C" void kernel_launch(void* const* d_in, const int* in_sizes, int n_in,
                              void* d_out, int out_size, void* d_ws, size_t ws_size,
                              hipStream_t stream)
{
  const int* ids = (const int*)d_in[0];
  const int* am = (const int*)d_in[1];
  const float* tok_emb = (const float*)d_in[2];
  const float* pos_emb = (const float*)d_in[3];
  const float* eg = (const float*)d_in[4];
  const float* eb = (const float*)d_in[5];
  const float* Wqkv = (const float*)d_in[6];
  const float* bqkv = (const float*)d_in[7];
  const float* Wo = (const float*)d_in[8];
  const float* bo = (const float*)d_in[9];
  const float* g1 = (const float*)d_in[10];
  const float* b1n = (const float*)d_in[11];
  const float* W1 = (const float*)d_in[12];
  const float* b1f = (const float*)d_in[13];
  const float* W2 = (const float*)d_in[14];
  const float* b2f = (const float*)d_in[15];
  const float* g2 = (const float*)d_in[16];
  const float* b2n = (const float*)d_in[17];

  char* ws = (char*)d_ws;
  float* x_f   = (float*)(ws);                  // residual stream (f32)
  short* x_b   = (short*)(ws + 12582912);       // residual (bf16)
  float* x2_f  = (float*)(ws + 18874368);       // post-LN1 (f32)
  short* x2_b  = (short*)(ws + 31457280);       // post-LN1 (bf16)
  short* pp0   = (short*)(ws + 37748736);       // split-K partial 0
  short* pp1   = (short*)(ws + 37748736 + 6291456);
  short* qkv   = (short*)(ws + 50331648);       // QKV (bf16, 18.9MB)
  short* pp2   = (short*)(ws + 50331648);       // partial 2 (aliases dead qkv)
  short* pp3   = (short*)(ws + 50331648 + 6291456);
  short* attn  = (short*)(ws + 69206016);       // attn out
  short* hb    = (short*)(ws + 75497472);       // FFN1 out (25MB)
  short* wqkvT = (short*)(ws + 100663296);
  short* woT   = (short*)(ws + 104202240);
  short* w1T   = (short*)(ws + 105381888);
  short* w2T   = (short*)(ws + 110100480);      // end ~109.5 MB

  embed_ln_k<<<4096, 256, 0, stream>>>(ids, tok_emb, pos_emb, eg, eb, x_f, x_b);

  for (int l = 0; l < 12; ++l) {
    transpose_all_k<<<1728, 256, 0, stream>>>(
        Wqkv + (size_t)l * 768 * 2304, Wo + (size_t)l * 768 * 768,
        W1 + (size_t)l * 768 * 3072, W2 + (size_t)l * 3072 * 768,
        wqkvT, woT, w1T, w2T);

    gemm_bt<128, 0><<<dim3(18, 32), 256, 0, stream>>>(
        x_b, wqkvT, bqkv + (size_t)l * 2304, qkv, 4096, 2304, 768);
    attn_k<<<dim3(8, 12, 8), 256, 0, stream>>>(qkv, am, attn);

    gemm_sk<<<dim3(6, 32, 4), 256, 0, stream>>>(
        attn, woT, pp0, pp1, pp2, pp3, 4096, 768, 768, 192);
    ln2_k<<<4096, 256, 0, stream>>>(
        pp0, pp1, pp2, pp3, bo + (size_t)l * 768, x_f,
        g1 + (size_t)l * 768, b1n + (size_t)l * 768, x2_f, x2_b);

    gemm_bt<128, 1><<<dim3(24, 32), 256, 0, stream>>>(
        x2_b, w1T, b1f + (size_t)l * 3072, hb, 4096, 3072, 768);

    gemm_sk<<<dim3(6, 32, 4), 256, 0, stream>>>(
        hb, w2T, pp0, pp1, pp2, pp3, 4096, 768, 3072, 768);
    ln2_k<<<4096, 256, 0, stream>>>(
        pp0, pp1, pp2, pp3, b2f + (size_t)l * 768, x2_f,
        g2 + (size_t)l * 768, b2n + (size_t)l * 768, x_f, x_b);
  }

  gather_k<<<8, 512, 0, stream>>>(ids, x_f, (float*)d_out);
}

// Round 13
// 2105.129 us; speedup vs baseline: 1.1247x; 1.0938x over previous
//
#include <hip/hip_runtime.h>
#include <hip/hip_bf16.h>

#define DEV static __device__ __forceinline__

using short8 = __attribute__((ext_vector_type(8))) short;
using f32x4 = __attribute__((ext_vector_type(4))) float;

DEV short f2bf(float f) {
  union { float f; unsigned u; } x; x.f = f;
  unsigned r = x.u + 0x7fffu + ((x.u >> 16) & 1u);
  return (short)(r >> 16);
}

DEV float bf2f(short s) {
  union { unsigned u; float f; } x; x.u = ((unsigned)(unsigned short)s) << 16;
  return x.f;
}

DEV void gload16(const void* g, void* lds) {
  __builtin_amdgcn_global_load_lds(
      (const __attribute__((address_space(1))) void*)g,
      (__attribute__((address_space(3))) void*)lds, 16, 0, 0);
}

// Abramowitz-Stegun 7.1.26 erf, |err| <= 1.5e-7
DEV float erf_fast(float x) {
  float ax = fabsf(x);
  float t = __fdividef(1.f, 1.f + 0.3275911f * ax);
  float y = t * (0.254829592f + t * (-0.284496736f +
            t * (1.421413741f + t * (-1.453152027f + t * 1.061405429f))));
  float r = 1.f - y * __expf(-ax * ax);
  return copysignf(r, x);
}

// ---------------- merged per-layer weight transpose: f32 [K][N] -> bf16 [N][K]
__global__ __launch_bounds__(256) void transpose_all_k(
    const float* __restrict__ Wqkv, const float* __restrict__ Wo,
    const float* __restrict__ W1, const float* __restrict__ W2,
    short* __restrict__ wqkvT, short* __restrict__ woT,
    short* __restrict__ w1T, short* __restrict__ w2T)
{
  __shared__ short t[64][76];
  const int b = blockIdx.x, tid = threadIdx.x;
  const float* in; short* out; int K, N, tt, nt;
  if (b < 432)       { in = Wqkv; out = wqkvT; K = 768;  N = 2304; tt = b;        nt = 36; }
  else if (b < 576)  { in = Wo;   out = woT;   K = 768;  N = 768;  tt = b - 432;  nt = 12; }
  else if (b < 1152) { in = W1;   out = w1T;   K = 768;  N = 3072; tt = b - 576;  nt = 48; }
  else               { in = W2;   out = w2T;   K = 3072; N = 768;  tt = b - 1152; nt = 12; }
  const int n0 = (tt % nt) * 64, k0 = (tt / nt) * 64;
  #pragma unroll
  for (int p = 0; p < 4; ++p) {
    int r = p * 16 + (tid >> 4), c4 = tid & 15;
    float4 v = *reinterpret_cast<const float4*>(in + (size_t)(k0 + r) * N + n0 + c4 * 4);
    t[r][c4 * 4 + 0] = f2bf(v.x);
    t[r][c4 * 4 + 1] = f2bf(v.y);
    t[r][c4 * 4 + 2] = f2bf(v.z);
    t[r][c4 * 4 + 3] = f2bf(v.w);
  }
  __syncthreads();
  #pragma unroll
  for (int q = 0; q < 2; ++q) {
    int n = tid >> 2, kc = (tid & 3) + q * 4;
    short8 o;
    #pragma unroll
    for (int j = 0; j < 8; ++j) o[j] = t[kc * 8 + j][n];
    *reinterpret_cast<short8*>(out + (size_t)(n0 + n) * K + k0 + kc * 8) = o;
  }
}

// ---------------- wide GEMM: BM=128 x BN=256, 8 waves (2x4), BK=64 as 2x32.
// Same sync skeleton as proven r8 gemm_bt. EPI 0: bias->bf16; 1: bias+gelu->bf16
template <int EPI>
__global__ __launch_bounds__(512) void gemm_wide(
    const short* __restrict__ A, const short* __restrict__ Bt,
    const float* __restrict__ bias, void* __restrict__ Cout,
    int M, int Nn, int K)
{
  __shared__ short As[2 * 128 * 32];   // 16 KB
  __shared__ short Bs[2 * 256 * 32];   // 32 KB
  const int tid = threadIdx.x, lane = tid & 63, w = tid >> 6;  // 8 waves
  const int wr = w >> 2, wc = w & 3;   // 2 x 4 wave grid, each 64x64 out
  const int l15 = lane & 15, l4 = lane >> 4;
  const int m0 = blockIdx.y * 128, n0 = blockIdx.x * 256;
  const int crow = lane >> 2, ccol = (lane & 3) * 8;

  f32x4 acc[4][4] = {};

  for (int k0 = 0; k0 < K; k0 += 64) {
    #pragma unroll
    for (int ks = 0; ks < 2; ++ks) {
      // A: 8 x 1KB chunks, wave w stages chunk w (rows w*16..w*16+15)
      gload16(A + (size_t)(m0 + w * 16 + crow) * K + k0 + ks * 32 + ccol,
              &As[ks * 4096 + w * 512]);
      // B: 16 chunks, wave w stages 2w, 2w+1
      #pragma unroll
      for (int s = 0; s < 2; ++s) {
        int c = w * 2 + s;
        gload16(Bt + (size_t)(n0 + c * 16 + crow) * K + k0 + ks * 32 + ccol,
                &Bs[ks * 8192 + c * 512]);
      }
    }
    __syncthreads();

    #pragma unroll
    for (int ks = 0; ks < 2; ++ks) {
      short8 af[4], bfr[4];
      #pragma unroll
      for (int i = 0; i < 4; ++i)
        af[i] = *reinterpret_cast<const short8*>(
            &As[ks * 4096 + (wr * 64 + i * 16 + l15) * 32 + l4 * 8]);
      #pragma unroll
      for (int j = 0; j < 4; ++j)
        bfr[j] = *reinterpret_cast<const short8*>(
            &Bs[ks * 8192 + (wc * 64 + j * 16 + l15) * 32 + l4 * 8]);
      #pragma unroll
      for (int i = 0; i < 4; ++i)
        #pragma unroll
        for (int j = 0; j < 4; ++j)
          acc[i][j] = __builtin_amdgcn_mfma_f32_16x16x32_bf16(af[i], bfr[j], acc[i][j], 0, 0, 0);
    }
    __syncthreads();
  }

  #pragma unroll
  for (int i = 0; i < 4; ++i) {
    #pragma unroll
    for (int j = 0; j < 4; ++j) {
      #pragma unroll
      for (int r = 0; r < 4; ++r) {
        int row = m0 + wr * 64 + i * 16 + l4 * 4 + r;
        int col = n0 + wc * 64 + j * 16 + l15;
        float v = acc[i][j][r] + bias[col];
        if constexpr (EPI == 1) v = 0.5f * v * (1.0f + erf_fast(v * 0.70710678118654752f));
        ((short*)Cout)[(size_t)row * Nn + col] = f2bf(v);
      }
    }
  }
}

// ---------------- split-K GEMM (BK=64, 4-way): bf16 partials, z in {0..3}
__global__ __launch_bounds__(256) void gemm_sk(
    const short* __restrict__ A, const short* __restrict__ Bt,
    short* __restrict__ p0, short* __restrict__ p1,
    short* __restrict__ p2, short* __restrict__ p3,
    int M, int Nn, int Kstride, int Klen)
{
  __shared__ short As[2 * 128 * 32];
  __shared__ short Bs[2 * 128 * 32];
  const int tid = threadIdx.x, lane = tid & 63, w = tid >> 6;
  const int wr = w >> 1, wc = w & 1;
  const int l15 = lane & 15, l4 = lane >> 4;
  const int m0 = blockIdx.y * 128, n0 = blockIdx.x * 128;
  const int koff = blockIdx.z * Klen;
  const int crow = lane >> 2, ccol = (lane & 3) * 8;

  f32x4 acc[4][4] = {};

  for (int k0 = 0; k0 < Klen; k0 += 64) {
    #pragma unroll
    for (int ks = 0; ks < 2; ++ks) {
      #pragma unroll
      for (int s = 0; s < 2; ++s) {
        int c = w * 2 + s;
        gload16(A + (size_t)(m0 + c * 16 + crow) * Kstride + koff + k0 + ks * 32 + ccol,
                &As[ks * 4096 + c * 512]);
      }
      #pragma unroll
      for (int s = 0; s < 2; ++s) {
        int c = w * 2 + s;
        gload16(Bt + (size_t)(n0 + c * 16 + crow) * Kstride + koff + k0 + ks * 32 + ccol,
                &Bs[ks * 4096 + c * 512]);
      }
    }
    __syncthreads();

    #pragma unroll
    for (int ks = 0; ks < 2; ++ks) {
      short8 af[4], bfr[4];
      #pragma unroll
      for (int i = 0; i < 4; ++i)
        af[i] = *reinterpret_cast<const short8*>(
            &As[ks * 4096 + (wr * 64 + i * 16 + l15) * 32 + l4 * 8]);
      #pragma unroll
      for (int j = 0; j < 4; ++j)
        bfr[j] = *reinterpret_cast<const short8*>(
            &Bs[ks * 4096 + (wc * 64 + j * 16 + l15) * 32 + l4 * 8]);
      #pragma unroll
      for (int i = 0; i < 4; ++i)
        #pragma unroll
        for (int j = 0; j < 4; ++j)
          acc[i][j] = __builtin_amdgcn_mfma_f32_16x16x32_bf16(af[i], bfr[j], acc[i][j], 0, 0, 0);
    }
    __syncthreads();
  }

  short* P = (blockIdx.z == 0) ? p0 : (blockIdx.z == 1) ? p1 : (blockIdx.z == 2) ? p2 : p3;
  #pragma unroll
  for (int i = 0; i < 4; ++i)
    #pragma unroll
    for (int j = 0; j < 4; ++j)
      #pragma unroll
      for (int r = 0; r < 4; ++r) {
        int row = m0 + wr * 64 + i * 16 + l4 * 4 + r;
        int col = n0 + wc * 64 + j * 16 + l15;
        P[(size_t)row * Nn + col] = f2bf(acc[i][j][r]);
      }
}

// ---------------- Flash attention (round-8 proven form, KVBLK=64)
__global__ __launch_bounds__(256) void attn_k(
    const short* __restrict__ qkv, const int* __restrict__ amask,
    short* __restrict__ out)
{
  __shared__ short Kl[64][72];
  __shared__ short Vt[64][68];
  __shared__ short Pl[4][16][72];
  const int b = blockIdx.z, h = blockIdx.y, qt = blockIdx.x;
  const int tid = threadIdx.x, lane = tid & 63, w = tid >> 6;
  const int l15 = lane & 15, l4 = lane >> 4;
  const int tok0 = b * 512;
  const int q0 = qt * 64 + w * 16;

  short8 qf[2];
  #pragma unroll
  for (int kk = 0; kk < 2; ++kk)
    qf[kk] = *reinterpret_cast<const short8*>(
        qkv + (size_t)(tok0 + q0 + l15) * 2304 + h * 64 + kk * 32 + l4 * 8);

  f32x4 oacc[4] = {};
  float mrow[4], lrow[4];
  #pragma unroll
  for (int r = 0; r < 4; ++r) { mrow[r] = -1e30f; lrow[r] = 0.f; }

  for (int kt0 = 0; kt0 < 512; kt0 += 64) {
    #pragma unroll
    for (int i = 0; i < 2; ++i) {
      int c = tid + i * 256;
      int r = c >> 3, dc = c & 7;
      short8 v = *reinterpret_cast<const short8*>(
          qkv + (size_t)(tok0 + kt0 + r) * 2304 + 768 + h * 64 + dc * 8);
      *reinterpret_cast<short8*>(&Kl[r][dc * 8]) = v;
    }
    #pragma unroll
    for (int i = 0; i < 2; ++i) {
      int c = tid + i * 256;
      int r = c >> 3, dc = c & 7;
      short8 v = *reinterpret_cast<const short8*>(
          qkv + (size_t)(tok0 + kt0 + r) * 2304 + 1536 + h * 64 + dc * 8);
      #pragma unroll
      for (int j = 0; j < 8; ++j) Vt[dc * 8 + j][r] = v[j];
    }
    __syncthreads();

    f32x4 sacc[4] = {};
    #pragma unroll
    for (int t = 0; t < 4; ++t) {
      #pragma unroll
      for (int kk = 0; kk < 2; ++kk) {
        short8 kf = *reinterpret_cast<const short8*>(&Kl[t * 16 + l15][kk * 32 + l4 * 8]);
        sacc[t] = __builtin_amdgcn_mfma_f32_16x16x32_bf16(qf[kk], kf, sacc[t], 0, 0, 0);
      }
    }
    float p[4][4];
    #pragma unroll
    for (int t = 0; t < 4; ++t) {
      int ktok = kt0 + t * 16 + l15;
      float biasv = amask[b * 512 + ktok] ? 0.f : -1e9f;
      #pragma unroll
      for (int r = 0; r < 4; ++r) p[t][r] = sacc[t][r] * 0.125f + biasv;
    }
    #pragma unroll
    for (int r = 0; r < 4; ++r) {
      float mx = fmaxf(fmaxf(p[0][r], p[1][r]), fmaxf(p[2][r], p[3][r]));
      #pragma unroll
      for (int s = 1; s <= 8; s <<= 1) mx = fmaxf(mx, __shfl_xor(mx, s, 64));
      float mnew = fmaxf(mrow[r], mx);
      float alpha = __expf(mrow[r] - mnew);
      mrow[r] = mnew;
      float sum = 0.f;
      #pragma unroll
      for (int t = 0; t < 4; ++t) { p[t][r] = __expf(p[t][r] - mnew); sum += p[t][r]; }
      #pragma unroll
      for (int s = 1; s <= 8; s <<= 1) sum += __shfl_xor(sum, s, 64);
      lrow[r] = lrow[r] * alpha + sum;
      #pragma unroll
      for (int t = 0; t < 4; ++t) oacc[t][r] *= alpha;
    }
    #pragma unroll
    for (int t = 0; t < 4; ++t)
      #pragma unroll
      for (int r = 0; r < 4; ++r)
        Pl[w][l4 * 4 + r][t * 16 + l15] = f2bf(p[t][r]);
    #pragma unroll
    for (int kk = 0; kk < 2; ++kk) {
      short8 pf = *reinterpret_cast<const short8*>(&Pl[w][l15][kk * 32 + l4 * 8]);
      #pragma unroll
      for (int t = 0; t < 4; ++t) {
        const unsigned* vp = reinterpret_cast<const unsigned*>(&Vt[t * 16 + l15][0]);
        union { short8 s; unsigned u[4]; } vu;
        #pragma unroll
        for (int w2 = 0; w2 < 4; ++w2) vu.u[w2] = vp[kk * 16 + l4 * 4 + w2];
        oacc[t] = __builtin_amdgcn_mfma_f32_16x16x32_bf16(pf, vu.s, oacc[t], 0, 0, 0);
      }
    }
    __syncthreads();
  }

  #pragma unroll
  for (int t = 0; t < 4; ++t)
    #pragma unroll
    for (int r = 0; r < 4; ++r) {
      int tok = tok0 + q0 + l4 * 4 + r;
      int dh = t * 16 + l15;
      out[(size_t)tok * 768 + h * 64 + dh] = f2bf(oacc[t][r] / lrow[r]);
    }
}

// ---------------- LN of (p0+p1+p2+p3 + bias + resid): bf16 partials -> f32 + bf16 out
__global__ __launch_bounds__(256) void ln2_k(
    const short* __restrict__ p0, const short* __restrict__ p1,
    const short* __restrict__ p2, const short* __restrict__ p3,
    const float* __restrict__ bias, const float* __restrict__ resid,
    const float* __restrict__ g, const float* __restrict__ be,
    float* __restrict__ xf, short* __restrict__ xb)
{
  const int t = blockIdx.x, tid = threadIdx.x;
  const size_t base = (size_t)t * 768;
  float v[3], s = 0.f, ss = 0.f;
  #pragma unroll
  for (int i = 0; i < 3; ++i) {
    int c = tid + i * 256;
    v[i] = (bf2f(p0[base + c]) + bf2f(p1[base + c]))
         + (bf2f(p2[base + c]) + bf2f(p3[base + c]))
         + bias[c] + resid[base + c];
    s += v[i]; ss += v[i] * v[i];
  }
  __shared__ float red[4][2];
  #pragma unroll
  for (int m = 1; m <= 32; m <<= 1) { s += __shfl_xor(s, m, 64); ss += __shfl_xor(ss, m, 64); }
  int w = tid >> 6;
  if ((tid & 63) == 0) { red[w][0] = s; red[w][1] = ss; }
  __syncthreads();
  s = red[0][0] + red[1][0] + red[2][0] + red[3][0];
  ss = red[0][1] + red[1][1] + red[2][1] + red[3][1];
  float mean = s * (1.f / 768.f);
  float var = ss * (1.f / 768.f) - mean * mean;
  float rs = rsqrtf(var + 1e-12f);
  #pragma unroll
  for (int i = 0; i < 3; ++i) {
    int c = tid + i * 256;
    float o = (v[i] - mean) * rs * g[c] + be[c];
    xf[base + c] = o;
    xb[base + c] = f2bf(o);
  }
}

// ---------------- embedding + LN (round-8 proven form)
__global__ __launch_bounds__(256) void embed_ln_k(
    const int* __restrict__ ids, const float* __restrict__ tok_emb,
    const float* __restrict__ pos_emb, const float* __restrict__ g,
    const float* __restrict__ be, float* __restrict__ xf, short* __restrict__ xb)
{
  const int t = blockIdx.x, tid = threadIdx.x;
  const int id = ids[t], sp = t & 511;
  float v[3], s = 0.f, ss = 0.f;
  #pragma unroll
  for (int i = 0; i < 3; ++i) {
    int c = tid + i * 256;
    v[i] = tok_emb[(size_t)id * 768 + c] + pos_emb[(size_t)sp * 768 + c];
    s += v[i]; ss += v[i] * v[i];
  }
  __shared__ float red[4][2];
  #pragma unroll
  for (int m = 1; m <= 32; m <<= 1) { s += __shfl_xor(s, m, 64); ss += __shfl_xor(ss, m, 64); }
  int w = tid >> 6;
  if ((tid & 63) == 0) { red[w][0] = s; red[w][1] = ss; }
  __syncthreads();
  s = red[0][0] + red[1][0] + red[2][0] + red[3][0];
  ss = red[0][1] + red[1][1] + red[2][1] + red[3][1];
  float mean = s * (1.f / 768.f);
  float var = ss * (1.f / 768.f) - mean * mean;
  float rs = rsqrtf(var + 1e-12f);
  #pragma unroll
  for (int i = 0; i < 3; ++i) {
    int c = tid + i * 256;
    float o = (v[i] - mean) * rs * g[c] + be[c];
    xf[(size_t)t * 768 + c] = o;
    xb[(size_t)t * 768 + c] = f2bf(o);
  }
}

// ---------------- gather/scatter (parallel): cls + sentinel rows -> out[8][64][768]
__global__ __launch_bounds__(512) void gather_k(
    const int* __restrict__ ids, const float* __restrict__ x, float* __restrict__ out)
{
  const int doc = blockIdx.x, tid = threadIdx.x;
  const int lane = tid & 63, w = tid >> 6;
  __shared__ int src[64];
  __shared__ int wave_sent[8];
  __shared__ int cls_pos;
  if (tid < 64) src[tid] = -1;
  if (tid == 0) cls_pos = 0x7fffffff;
  __syncthreads();

  const int id = ids[doc * 512 + tid];
  const bool is_sent = (id == 103);
  const unsigned long long m = __ballot(is_sent);
  if (lane == 0) wave_sent[w] = __popcll(m);
  if (id == 102) atomicMin(&cls_pos, tid);
  __syncthreads();

  int total = 0, prefix = 0;
  #pragma unroll
  for (int i = 0; i < 8; ++i) {
    int c = wave_sent[i];
    if (i < w) prefix += c;
    total += c;
  }
  if (is_sent) {
    unsigned long long lt = lane ? (~0ULL >> (64 - lane)) : 0ULL;
    int d = 1 + prefix + __popcll(m & lt);
    if (d < total && d < 64) src[d] = tid;
  }
  if (tid == 0 && total > 0 && cls_pos != 0x7fffffff) src[0] = cls_pos;
  __syncthreads();

  for (int i = tid; i < 64 * 192; i += 512) {
    int row = i / 192, c4 = i - row * 192;
    int sp = src[row];
    float4 v = make_float4(0.f, 0.f, 0.f, 0.f);
    if (sp >= 0)
      v = reinterpret_cast<const float4*>(x + (size_t)(doc * 512 + sp) * 768)[c4];
    reinterpret_cast<float4*>(out + (size_t)doc * 64 * 768)[i] = v;
  }
}

extern "C" void kernel_launch(void* const* d_in, const int* in_sizes, int n_in,
                              void* d_out, int out_size, void* d_ws, size_t ws_size,
                              hipStream_t stream)
{
  const int* ids = (const int*)d_in[0];
  const int* am = (const int*)d_in[1];
  const float* tok_emb = (const float*)d_in[2];
  const float* pos_emb = (const float*)d_in[3];
  const float* eg = (const float*)d_in[4];
  const float* eb = (const float*)d_in[5];
  const float* Wqkv = (const float*)d_in[6];
  const float* bqkv = (const float*)d_in[7];
  const float* Wo = (const float*)d_in[8];
  const float* bo = (const float*)d_in[9];
  const float* g1 = (const float*)d_in[10];
  const float* b1n = (const float*)d_in[11];
  const float* W1 = (const float*)d_in[12];
  const float* b1f = (const float*)d_in[13];
  const float* W2 = (const float*)d_in[14];
  const float* b2f = (const float*)d_in[15];
  const float* g2 = (const float*)d_in[16];
  const float* b2n = (const float*)d_in[17];

  char* ws = (char*)d_ws;
  float* x_f   = (float*)(ws);                  // residual stream (f32)
  short* x_b   = (short*)(ws + 12582912);       // residual (bf16)
  float* x2_f  = (float*)(ws + 18874368);       // post-LN1 (f32)
  short* x2_b  = (short*)(ws + 31457280);       // post-LN1 (bf16)
  short* pp0   = (short*)(ws + 37748736);       // split-K partial 0
  short* pp1   = (short*)(ws + 37748736 + 6291456);
  short* qkv   = (short*)(ws + 50331648);       // QKV (bf16, 18.9MB)
  short* pp2   = (short*)(ws + 50331648);       // partial 2 (aliases dead qkv)
  short* pp3   = (short*)(ws + 50331648 + 6291456);
  short* attn  = (short*)(ws + 69206016);       // attn out
  short* hb    = (short*)(ws + 75497472);       // FFN1 out (25MB)
  short* wqkvT = (short*)(ws + 100663296);
  short* woT   = (short*)(ws + 104202240);
  short* w1T   = (short*)(ws + 105381888);
  short* w2T   = (short*)(ws + 110100480);      // end ~109.5 MB

  embed_ln_k<<<4096, 256, 0, stream>>>(ids, tok_emb, pos_emb, eg, eb, x_f, x_b);

  for (int l = 0; l < 12; ++l) {
    transpose_all_k<<<1728, 256, 0, stream>>>(
        Wqkv + (size_t)l * 768 * 2304, Wo + (size_t)l * 768 * 768,
        W1 + (size_t)l * 768 * 3072, W2 + (size_t)l * 3072 * 768,
        wqkvT, woT, w1T, w2T);

    gemm_wide<0><<<dim3(9, 32), 512, 0, stream>>>(
        x_b, wqkvT, bqkv + (size_t)l * 2304, qkv, 4096, 2304, 768);
    attn_k<<<dim3(8, 12, 8), 256, 0, stream>>>(qkv, am, attn);

    gemm_sk<<<dim3(6, 32, 4), 256, 0, stream>>>(
        attn, woT, pp0, pp1, pp2, pp3, 4096, 768, 768, 192);
    ln2_k<<<4096, 256, 0, stream>>>(
        pp0, pp1, pp2, pp3, bo + (size_t)l * 768, x_f,
        g1 + (size_t)l * 768, b1n + (size_t)l * 768, x2_f, x2_b);

    gemm_wide<1><<<dim3(12, 32), 512, 0, stream>>>(
        x2_b, w1T, b1f + (size_t)l * 3072, hb, 4096, 3072, 768);

    gemm_sk<<<dim3(6, 32, 4), 256, 0, stream>>>(
        hb, w2T, pp0, pp1, pp2, pp3, 4096, 768, 3072, 768);
    ln2_k<<<4096, 256, 0, stream>>>(
        pp0, pp1, pp2, pp3, b2f + (size_t)l * 768, x2_f,
        g2 + (size_t)l * 768, b2n + (size_t)l * 768, x_f, x_b);
  }

  gather_k<<<8, 512, 0, stream>>>(ids, x_f, (float*)d_out);
}

// Round 14
// 2020.828 us; speedup vs baseline: 1.1716x; 1.0417x over previous
//
#include <hip/hip_runtime.h>
#include <hip/hip_bf16.h>

#define DEV static __device__ __forceinline__

using short8 = __attribute__((ext_vector_type(8))) short;
using f32x4 = __attribute__((ext_vector_type(4))) float;

DEV short f2bf(float f) {
  union { float f; unsigned u; } x; x.f = f;
  unsigned r = x.u + 0x7fffu + ((x.u >> 16) & 1u);
  return (short)(r >> 16);
}

DEV float bf2f(short s) {
  union { unsigned u; float f; } x; x.u = ((unsigned)(unsigned short)s) << 16;
  return x.f;
}

DEV void gload16(const void* g, void* lds) {
  __builtin_amdgcn_global_load_lds(
      (const __attribute__((address_space(1))) void*)g,
      (__attribute__((address_space(3))) void*)lds, 16, 0, 0);
}

// Abramowitz-Stegun 7.1.26 erf, |err| <= 1.5e-7
DEV float erf_fast(float x) {
  float ax = fabsf(x);
  float t = __fdividef(1.f, 1.f + 0.3275911f * ax);
  float y = t * (0.254829592f + t * (-0.284496736f +
            t * (1.421413741f + t * (-1.453152027f + t * 1.061405429f))));
  float r = 1.f - y * __expf(-ax * ax);
  return copysignf(r, x);
}

// ---------------- merged per-layer weight transpose: f32 [K][N] -> bf16 [N][K]
__global__ __launch_bounds__(256) void transpose_all_k(
    const float* __restrict__ Wqkv, const float* __restrict__ Wo,
    const float* __restrict__ W1, const float* __restrict__ W2,
    short* __restrict__ wqkvT, short* __restrict__ woT,
    short* __restrict__ w1T, short* __restrict__ w2T)
{
  __shared__ short t[64][76];
  const int b = blockIdx.x, tid = threadIdx.x;
  const float* in; short* out; int K, N, tt, nt;
  if (b < 432)       { in = Wqkv; out = wqkvT; K = 768;  N = 2304; tt = b;        nt = 36; }
  else if (b < 576)  { in = Wo;   out = woT;   K = 768;  N = 768;  tt = b - 432;  nt = 12; }
  else if (b < 1152) { in = W1;   out = w1T;   K = 768;  N = 3072; tt = b - 576;  nt = 48; }
  else               { in = W2;   out = w2T;   K = 3072; N = 768;  tt = b - 1152; nt = 12; }
  const int n0 = (tt % nt) * 64, k0 = (tt / nt) * 64;
  #pragma unroll
  for (int p = 0; p < 4; ++p) {
    int r = p * 16 + (tid >> 4), c4 = tid & 15;
    float4 v = *reinterpret_cast<const float4*>(in + (size_t)(k0 + r) * N + n0 + c4 * 4);
    t[r][c4 * 4 + 0] = f2bf(v.x);
    t[r][c4 * 4 + 1] = f2bf(v.y);
    t[r][c4 * 4 + 2] = f2bf(v.z);
    t[r][c4 * 4 + 3] = f2bf(v.w);
  }
  __syncthreads();
  #pragma unroll
  for (int q = 0; q < 2; ++q) {
    int n = tid >> 2, kc = (tid & 3) + q * 4;
    short8 o;
    #pragma unroll
    for (int j = 0; j < 8; ++j) o[j] = t[kc * 8 + j][n];
    *reinterpret_cast<short8*>(out + (size_t)(n0 + n) * K + k0 + kc * 8) = o;
  }
}

// ---------------- wide GEMM: BM=128 x BN=256, 8 waves (2x4), BK=64 as 2x32.
// EPI 0: bias->bf16; 1: bias+gelu->bf16
template <int EPI>
__global__ __launch_bounds__(512) void gemm_wide(
    const short* __restrict__ A, const short* __restrict__ Bt,
    const float* __restrict__ bias, void* __restrict__ Cout,
    int M, int Nn, int K)
{
  __shared__ short As[2 * 128 * 32];   // 16 KB
  __shared__ short Bs[2 * 256 * 32];   // 32 KB
  const int tid = threadIdx.x, lane = tid & 63, w = tid >> 6;  // 8 waves
  const int wr = w >> 2, wc = w & 3;   // 2 x 4 wave grid, each 64x64 out
  const int l15 = lane & 15, l4 = lane >> 4;
  const int m0 = blockIdx.y * 128, n0 = blockIdx.x * 256;
  const int crow = lane >> 2, ccol = (lane & 3) * 8;

  f32x4 acc[4][4] = {};

  for (int k0 = 0; k0 < K; k0 += 64) {
    #pragma unroll
    for (int ks = 0; ks < 2; ++ks) {
      gload16(A + (size_t)(m0 + w * 16 + crow) * K + k0 + ks * 32 + ccol,
              &As[ks * 4096 + w * 512]);
      #pragma unroll
      for (int s = 0; s < 2; ++s) {
        int c = w * 2 + s;
        gload16(Bt + (size_t)(n0 + c * 16 + crow) * K + k0 + ks * 32 + ccol,
                &Bs[ks * 8192 + c * 512]);
      }
    }
    __syncthreads();

    #pragma unroll
    for (int ks = 0; ks < 2; ++ks) {
      short8 af[4], bfr[4];
      #pragma unroll
      for (int i = 0; i < 4; ++i)
        af[i] = *reinterpret_cast<const short8*>(
            &As[ks * 4096 + (wr * 64 + i * 16 + l15) * 32 + l4 * 8]);
      #pragma unroll
      for (int j = 0; j < 4; ++j)
        bfr[j] = *reinterpret_cast<const short8*>(
            &Bs[ks * 8192 + (wc * 64 + j * 16 + l15) * 32 + l4 * 8]);
      #pragma unroll
      for (int i = 0; i < 4; ++i)
        #pragma unroll
        for (int j = 0; j < 4; ++j)
          acc[i][j] = __builtin_amdgcn_mfma_f32_16x16x32_bf16(af[i], bfr[j], acc[i][j], 0, 0, 0);
    }
    __syncthreads();
  }

  #pragma unroll
  for (int i = 0; i < 4; ++i) {
    #pragma unroll
    for (int j = 0; j < 4; ++j) {
      #pragma unroll
      for (int r = 0; r < 4; ++r) {
        int row = m0 + wr * 64 + i * 16 + l4 * 4 + r;
        int col = n0 + wc * 64 + j * 16 + l15;
        float v = acc[i][j][r] + bias[col];
        if constexpr (EPI == 1) v = 0.5f * v * (1.0f + erf_fast(v * 0.70710678118654752f));
        ((short*)Cout)[(size_t)row * Nn + col] = f2bf(v);
      }
    }
  }
}

// ---------------- wide split-K GEMM: BM=128 x BN=256, 8 waves, 4-way K-split.
// bf16 partials, blockIdx.z picks the partial buffer. Same skeleton as gemm_wide.
__global__ __launch_bounds__(512) void gemm_wide_sk(
    const short* __restrict__ A, const short* __restrict__ Bt,
    short* __restrict__ p0, short* __restrict__ p1,
    short* __restrict__ p2, short* __restrict__ p3,
    int M, int Nn, int Kstride, int Klen)
{
  __shared__ short As[2 * 128 * 32];
  __shared__ short Bs[2 * 256 * 32];
  const int tid = threadIdx.x, lane = tid & 63, w = tid >> 6;
  const int wr = w >> 2, wc = w & 3;
  const int l15 = lane & 15, l4 = lane >> 4;
  const int m0 = blockIdx.y * 128, n0 = blockIdx.x * 256;
  const int koff = blockIdx.z * Klen;
  const int crow = lane >> 2, ccol = (lane & 3) * 8;

  f32x4 acc[4][4] = {};

  for (int k0 = 0; k0 < Klen; k0 += 64) {
    #pragma unroll
    for (int ks = 0; ks < 2; ++ks) {
      gload16(A + (size_t)(m0 + w * 16 + crow) * Kstride + koff + k0 + ks * 32 + ccol,
              &As[ks * 4096 + w * 512]);
      #pragma unroll
      for (int s = 0; s < 2; ++s) {
        int c = w * 2 + s;
        gload16(Bt + (size_t)(n0 + c * 16 + crow) * Kstride + koff + k0 + ks * 32 + ccol,
                &Bs[ks * 8192 + c * 512]);
      }
    }
    __syncthreads();

    #pragma unroll
    for (int ks = 0; ks < 2; ++ks) {
      short8 af[4], bfr[4];
      #pragma unroll
      for (int i = 0; i < 4; ++i)
        af[i] = *reinterpret_cast<const short8*>(
            &As[ks * 4096 + (wr * 64 + i * 16 + l15) * 32 + l4 * 8]);
      #pragma unroll
      for (int j = 0; j < 4; ++j)
        bfr[j] = *reinterpret_cast<const short8*>(
            &Bs[ks * 8192 + (wc * 64 + j * 16 + l15) * 32 + l4 * 8]);
      #pragma unroll
      for (int i = 0; i < 4; ++i)
        #pragma unroll
        for (int j = 0; j < 4; ++j)
          acc[i][j] = __builtin_amdgcn_mfma_f32_16x16x32_bf16(af[i], bfr[j], acc[i][j], 0, 0, 0);
    }
    __syncthreads();
  }

  short* P = (blockIdx.z == 0) ? p0 : (blockIdx.z == 1) ? p1 : (blockIdx.z == 2) ? p2 : p3;
  #pragma unroll
  for (int i = 0; i < 4; ++i)
    #pragma unroll
    for (int j = 0; j < 4; ++j)
      #pragma unroll
      for (int r = 0; r < 4; ++r) {
        int row = m0 + wr * 64 + i * 16 + l4 * 4 + r;
        int col = n0 + wc * 64 + j * 16 + l15;
        P[(size_t)row * Nn + col] = f2bf(acc[i][j][r]);
      }
}

// ---------------- Flash attention (round-8 proven form, KVBLK=64)
__global__ __launch_bounds__(256) void attn_k(
    const short* __restrict__ qkv, const int* __restrict__ amask,
    short* __restrict__ out)
{
  __shared__ short Kl[64][72];
  __shared__ short Vt[64][68];
  __shared__ short Pl[4][16][72];
  const int b = blockIdx.z, h = blockIdx.y, qt = blockIdx.x;
  const int tid = threadIdx.x, lane = tid & 63, w = tid >> 6;
  const int l15 = lane & 15, l4 = lane >> 4;
  const int tok0 = b * 512;
  const int q0 = qt * 64 + w * 16;

  short8 qf[2];
  #pragma unroll
  for (int kk = 0; kk < 2; ++kk)
    qf[kk] = *reinterpret_cast<const short8*>(
        qkv + (size_t)(tok0 + q0 + l15) * 2304 + h * 64 + kk * 32 + l4 * 8);

  f32x4 oacc[4] = {};
  float mrow[4], lrow[4];
  #pragma unroll
  for (int r = 0; r < 4; ++r) { mrow[r] = -1e30f; lrow[r] = 0.f; }

  for (int kt0 = 0; kt0 < 512; kt0 += 64) {
    #pragma unroll
    for (int i = 0; i < 2; ++i) {
      int c = tid + i * 256;
      int r = c >> 3, dc = c & 7;
      short8 v = *reinterpret_cast<const short8*>(
          qkv + (size_t)(tok0 + kt0 + r) * 2304 + 768 + h * 64 + dc * 8);
      *reinterpret_cast<short8*>(&Kl[r][dc * 8]) = v;
    }
    #pragma unroll
    for (int i = 0; i < 2; ++i) {
      int c = tid + i * 256;
      int r = c >> 3, dc = c & 7;
      short8 v = *reinterpret_cast<const short8*>(
          qkv + (size_t)(tok0 + kt0 + r) * 2304 + 1536 + h * 64 + dc * 8);
      #pragma unroll
      for (int j = 0; j < 8; ++j) Vt[dc * 8 + j][r] = v[j];
    }
    __syncthreads();

    f32x4 sacc[4] = {};
    #pragma unroll
    for (int t = 0; t < 4; ++t) {
      #pragma unroll
      for (int kk = 0; kk < 2; ++kk) {
        short8 kf = *reinterpret_cast<const short8*>(&Kl[t * 16 + l15][kk * 32 + l4 * 8]);
        sacc[t] = __builtin_amdgcn_mfma_f32_16x16x32_bf16(qf[kk], kf, sacc[t], 0, 0, 0);
      }
    }
    float p[4][4];
    #pragma unroll
    for (int t = 0; t < 4; ++t) {
      int ktok = kt0 + t * 16 + l15;
      float biasv = amask[b * 512 + ktok] ? 0.f : -1e9f;
      #pragma unroll
      for (int r = 0; r < 4; ++r) p[t][r] = sacc[t][r] * 0.125f + biasv;
    }
    #pragma unroll
    for (int r = 0; r < 4; ++r) {
      float mx = fmaxf(fmaxf(p[0][r], p[1][r]), fmaxf(p[2][r], p[3][r]));
      #pragma unroll
      for (int s = 1; s <= 8; s <<= 1) mx = fmaxf(mx, __shfl_xor(mx, s, 64));
      float mnew = fmaxf(mrow[r], mx);
      float alpha = __expf(mrow[r] - mnew);
      mrow[r] = mnew;
      float sum = 0.f;
      #pragma unroll
      for (int t = 0; t < 4; ++t) { p[t][r] = __expf(p[t][r] - mnew); sum += p[t][r]; }
      #pragma unroll
      for (int s = 1; s <= 8; s <<= 1) sum += __shfl_xor(sum, s, 64);
      lrow[r] = lrow[r] * alpha + sum;
      #pragma unroll
      for (int t = 0; t < 4; ++t) oacc[t][r] *= alpha;
    }
    #pragma unroll
    for (int t = 0; t < 4; ++t)
      #pragma unroll
      for (int r = 0; r < 4; ++r)
        Pl[w][l4 * 4 + r][t * 16 + l15] = f2bf(p[t][r]);
    #pragma unroll
    for (int kk = 0; kk < 2; ++kk) {
      short8 pf = *reinterpret_cast<const short8*>(&Pl[w][l15][kk * 32 + l4 * 8]);
      #pragma unroll
      for (int t = 0; t < 4; ++t) {
        const unsigned* vp = reinterpret_cast<const unsigned*>(&Vt[t * 16 + l15][0]);
        union { short8 s; unsigned u[4]; } vu;
        #pragma unroll
        for (int w2 = 0; w2 < 4; ++w2) vu.u[w2] = vp[kk * 16 + l4 * 4 + w2];
        oacc[t] = __builtin_amdgcn_mfma_f32_16x16x32_bf16(pf, vu.s, oacc[t], 0, 0, 0);
      }
    }
    __syncthreads();
  }

  #pragma unroll
  for (int t = 0; t < 4; ++t)
    #pragma unroll
    for (int r = 0; r < 4; ++r) {
      int tok = tok0 + q0 + l4 * 4 + r;
      int dh = t * 16 + l15;
      out[(size_t)tok * 768 + h * 64 + dh] = f2bf(oacc[t][r] / lrow[r]);
    }
}

// ---------------- LN of (p0+p1+p2+p3 + bias + resid): bf16 partials -> f32 + bf16 out
__global__ __launch_bounds__(256) void ln2_k(
    const short* __restrict__ p0, const short* __restrict__ p1,
    const short* __restrict__ p2, const short* __restrict__ p3,
    const float* __restrict__ bias, const float* __restrict__ resid,
    const float* __restrict__ g, const float* __restrict__ be,
    float* __restrict__ xf, short* __restrict__ xb)
{
  const int t = blockIdx.x, tid = threadIdx.x;
  const size_t base = (size_t)t * 768;
  float v[3], s = 0.f, ss = 0.f;
  #pragma unroll
  for (int i = 0; i < 3; ++i) {
    int c = tid + i * 256;
    v[i] = (bf2f(p0[base + c]) + bf2f(p1[base + c]))
         + (bf2f(p2[base + c]) + bf2f(p3[base + c]))
         + bias[c] + resid[base + c];
    s += v[i]; ss += v[i] * v[i];
  }
  __shared__ float red[4][2];
  #pragma unroll
  for (int m = 1; m <= 32; m <<= 1) { s += __shfl_xor(s, m, 64); ss += __shfl_xor(ss, m, 64); }
  int w = tid >> 6;
  if ((tid & 63) == 0) { red[w][0] = s; red[w][1] = ss; }
  __syncthreads();
  s = red[0][0] + red[1][0] + red[2][0] + red[3][0];
  ss = red[0][1] + red[1][1] + red[2][1] + red[3][1];
  float mean = s * (1.f / 768.f);
  float var = ss * (1.f / 768.f) - mean * mean;
  float rs = rsqrtf(var + 1e-12f);
  #pragma unroll
  for (int i = 0; i < 3; ++i) {
    int c = tid + i * 256;
    float o = (v[i] - mean) * rs * g[c] + be[c];
    xf[base + c] = o;
    xb[base + c] = f2bf(o);
  }
}

// ---------------- embedding + LN (round-8 proven form)
__global__ __launch_bounds__(256) void embed_ln_k(
    const int* __restrict__ ids, const float* __restrict__ tok_emb,
    const float* __restrict__ pos_emb, const float* __restrict__ g,
    const float* __restrict__ be, float* __restrict__ xf, short* __restrict__ xb)
{
  const int t = blockIdx.x, tid = threadIdx.x;
  const int id = ids[t], sp = t & 511;
  float v[3], s = 0.f, ss = 0.f;
  #pragma unroll
  for (int i = 0; i < 3; ++i) {
    int c = tid + i * 256;
    v[i] = tok_emb[(size_t)id * 768 + c] + pos_emb[(size_t)sp * 768 + c];
    s += v[i]; ss += v[i] * v[i];
  }
  __shared__ float red[4][2];
  #pragma unroll
  for (int m = 1; m <= 32; m <<= 1) { s += __shfl_xor(s, m, 64); ss += __shfl_xor(ss, m, 64); }
  int w = tid >> 6;
  if ((tid & 63) == 0) { red[w][0] = s; red[w][1] = ss; }
  __syncthreads();
  s = red[0][0] + red[1][0] + red[2][0] + red[3][0];
  ss = red[0][1] + red[1][1] + red[2][1] + red[3][1];
  float mean = s * (1.f / 768.f);
  float var = ss * (1.f / 768.f) - mean * mean;
  float rs = rsqrtf(var + 1e-12f);
  #pragma unroll
  for (int i = 0; i < 3; ++i) {
    int c = tid + i * 256;
    float o = (v[i] - mean) * rs * g[c] + be[c];
    xf[(size_t)t * 768 + c] = o;
    xb[(size_t)t * 768 + c] = f2bf(o);
  }
}

// ---------------- gather/scatter (parallel): cls + sentinel rows -> out[8][64][768]
__global__ __launch_bounds__(512) void gather_k(
    const int* __restrict__ ids, const float* __restrict__ x, float* __restrict__ out)
{
  const int doc = blockIdx.x, tid = threadIdx.x;
  const int lane = tid & 63, w = tid >> 6;
  __shared__ int src[64];
  __shared__ int wave_sent[8];
  __shared__ int cls_pos;
  if (tid < 64) src[tid] = -1;
  if (tid == 0) cls_pos = 0x7fffffff;
  __syncthreads();

  const int id = ids[doc * 512 + tid];
  const bool is_sent = (id == 103);
  const unsigned long long m = __ballot(is_sent);
  if (lane == 0) wave_sent[w] = __popcll(m);
  if (id == 102) atomicMin(&cls_pos, tid);
  __syncthreads();

  int total = 0, prefix = 0;
  #pragma unroll
  for (int i = 0; i < 8; ++i) {
    int c = wave_sent[i];
    if (i < w) prefix += c;
    total += c;
  }
  if (is_sent) {
    unsigned long long lt = lane ? (~0ULL >> (64 - lane)) : 0ULL;
    int d = 1 + prefix + __popcll(m & lt);
    if (d < total && d < 64) src[d] = tid;
  }
  if (tid == 0 && total > 0 && cls_pos != 0x7fffffff) src[0] = cls_pos;
  __syncthreads();

  for (int i = tid; i < 64 * 192; i += 512) {
    int row = i / 192, c4 = i - row * 192;
    int sp = src[row];
    float4 v = make_float4(0.f, 0.f, 0.f, 0.f);
    if (sp >= 0)
      v = reinterpret_cast<const float4*>(x + (size_t)(doc * 512 + sp) * 768)[c4];
    reinterpret_cast<float4*>(out + (size_t)doc * 64 * 768)[i] = v;
  }
}

extern "C" void kernel_launch(void* const* d_in, const int* in_sizes, int n_in,
                              void* d_out, int out_size, void* d_ws, size_t ws_size,
                              hipStream_t stream)
{
  const int* ids = (const int*)d_in[0];
  const int* am = (const int*)d_in[1];
  const float* tok_emb = (const float*)d_in[2];
  const float* pos_emb = (const float*)d_in[3];
  const float* eg = (const float*)d_in[4];
  const float* eb = (const float*)d_in[5];
  const float* Wqkv = (const float*)d_in[6];
  const float* bqkv = (const float*)d_in[7];
  const float* Wo = (const float*)d_in[8];
  const float* bo = (const float*)d_in[9];
  const float* g1 = (const float*)d_in[10];
  const float* b1n = (const float*)d_in[11];
  const float* W1 = (const float*)d_in[12];
  const float* b1f = (const float*)d_in[13];
  const float* W2 = (const float*)d_in[14];
  const float* b2f = (const float*)d_in[15];
  const float* g2 = (const float*)d_in[16];
  const float* b2n = (const float*)d_in[17];

  char* ws = (char*)d_ws;
  float* x_f   = (float*)(ws);                  // residual stream (f32)
  short* x_b   = (short*)(ws + 12582912);       // residual (bf16)
  float* x2_f  = (float*)(ws + 18874368);       // post-LN1 (f32)
  short* x2_b  = (short*)(ws + 31457280);       // post-LN1 (bf16)
  short* pp0   = (short*)(ws + 37748736);       // split-K partial 0
  short* pp1   = (short*)(ws + 37748736 + 6291456);
  short* qkv   = (short*)(ws + 50331648);       // QKV (bf16, 18.9MB)
  short* pp2   = (short*)(ws + 50331648);       // partial 2 (aliases dead qkv)
  short* pp3   = (short*)(ws + 50331648 + 6291456);
  short* attn  = (short*)(ws + 69206016);       // attn out
  short* hb    = (short*)(ws + 75497472);       // FFN1 out (25MB)
  short* wqkvT = (short*)(ws + 100663296);
  short* woT   = (short*)(ws + 104202240);
  short* w1T   = (short*)(ws + 105381888);
  short* w2T   = (short*)(ws + 110100480);      // end ~109.5 MB

  embed_ln_k<<<4096, 256, 0, stream>>>(ids, tok_emb, pos_emb, eg, eb, x_f, x_b);

  for (int l = 0; l < 12; ++l) {
    transpose_all_k<<<1728, 256, 0, stream>>>(
        Wqkv + (size_t)l * 768 * 2304, Wo + (size_t)l * 768 * 768,
        W1 + (size_t)l * 768 * 3072, W2 + (size_t)l * 3072 * 768,
        wqkvT, woT, w1T, w2T);

    gemm_wide<0><<<dim3(9, 32), 512, 0, stream>>>(
        x_b, wqkvT, bqkv + (size_t)l * 2304, qkv, 4096, 2304, 768);
    attn_k<<<dim3(8, 12, 8), 256, 0, stream>>>(qkv, am, attn);

    gemm_wide_sk<<<dim3(3, 32, 4), 512, 0, stream>>>(
        attn, woT, pp0, pp1, pp2, pp3, 4096, 768, 768, 192);
    ln2_k<<<4096, 256, 0, stream>>>(
        pp0, pp1, pp2, pp3, bo + (size_t)l * 768, x_f,
        g1 + (size_t)l * 768, b1n + (size_t)l * 768, x2_f, x2_b);

    gemm_wide<1><<<dim3(12, 32), 512, 0, stream>>>(
        x2_b, w1T, b1f + (size_t)l * 3072, hb, 4096, 3072, 768);

    gemm_wide_sk<<<dim3(3, 32, 4), 512, 0, stream>>>(
        hb, w2T, pp0, pp1, pp2, pp3, 4096, 768, 3072, 768);
    ln2_k<<<4096, 256, 0, stream>>>(
        pp0, pp1, pp2, pp3, b2f + (size_t)l * 768, x2_f,
        g2 + (size_t)l * 768, b2n + (size_t)l * 768, x_f, x_b);
  }

  gather_k<<<8, 512, 0, stream>>>(ids, x_f, (float*)d_out);
}